// Round 9
// baseline (254.073 us; speedup 1.0000x reference)
//
#include <hip/hip_runtime.h>
#include <hip/hip_bf16.h>
#include <math.h>

// Dims fixed by setup_inputs(): B=16, S=2048, D=1024, H=16, hd=64, P=8,
// cls=1, pma=8, recent=64, T=73.

#define Bn 16
#define Sn 2048
#define Dn 1024
#define Hn 16
#define Pn 8
#define Tn 73
#define RECn 64

typedef __attribute__((ext_vector_type(8))) short short8;
typedef __attribute__((ext_vector_type(4))) float f32x4;

__device__ __forceinline__ short f2bf(float x) {
    union { __hip_bfloat16 h; short s; } u;
    u.h = __float2bfloat16(x);   // native v_cvt, RNE
    return u.s;
}

// XOR swizzle: spreads row r's 16B slots across bank groups.
__device__ __forceinline__ int swzP(int row, int ks, int pitch) {
    return row * pitch + (ks ^ ((row & 7) << 3));
}

// ---------------------------------------------------------------- mask dtype detect
__global__ void detect_mask_kernel(const unsigned char* __restrict__ raw,
                                   int* __restrict__ flag) {
    __shared__ int any;
    if (threadIdx.x == 0) any = 0;
    __syncthreads();
    const uint4* r4 = (const uint4*)raw;
    int local = 0;
    for (int i = threadIdx.x; i < (Bn * Sn) / 16; i += blockDim.x) {
        uint4 w = r4[i];
        if ((w.x & 0xFFFFFF00u) | (w.y & 0xFFFFFF00u) |
            (w.z & 0xFFFFFF00u) | (w.w & 0xFFFFFF00u)) local = 1;
    }
    if (local) any = 1; // benign race
    __syncthreads();
    if (threadIdx.x == 0) *flag = any;
}

__global__ void canon_mask_kernel(const void* __restrict__ raw,
                                  const int* __restrict__ flag,
                                  unsigned char* __restrict__ canon) {
    int i = blockIdx.x * blockDim.x + threadIdx.x;
    if (i >= Bn * Sn) return;
    unsigned char v;
    if (*flag)
        v = ((const unsigned char*)raw)[i] ? 1 : 0;
    else
        v = ((const int*)raw)[i] ? 1 : 0;
    canon[i] = v;
}

// ---------------------------------------------------------------- prep
__global__ void prep_kernel(const unsigned char* __restrict__ valid,
                            int* __restrict__ totals, int* __restrict__ rsrc,
                            float* __restrict__ maskf) {
    int b = blockIdx.x, t = threadIdx.x;
    const int SP = Sn - 1; // 2047
    __shared__ int lc[256];
    if (t < RECn) rsrc[b * RECn + t] = -1;

    int base = t * 8;
    unsigned char m[8];
    int cnt = 0;
#pragma unroll
    for (int i = 0; i < 8; i++) {
        int idx = base + i;
        m[i] = (idx < SP) ? valid[(size_t)b * Sn + 1 + idx] : (unsigned char)0;
        cnt += m[i] ? 1 : 0;
    }
    lc[t] = cnt;
    __syncthreads();
    for (int off = 1; off < 256; off <<= 1) {
        int add = (t >= off) ? lc[t - off] : 0;
        __syncthreads();
        lc[t] += add;
        __syncthreads();
    }
    int total = lc[255];
    int run = lc[t] - cnt; // exclusive prefix
#pragma unroll
    for (int i = 0; i < 8; i++) {
        if (m[i]) {
            run++;
            int rank = total - run;
            if (rank < RECn) rsrc[b * RECn + (RECn - 1 - rank)] = base + i + 1;
        }
    }
    if (t == 0) totals[b] = total;
    if (t < Tn) {
        float mv;
        if (t == 0) mv = valid[(size_t)b * Sn] ? 1.0f : 0.0f;
        else if (t < 1 + Pn) mv = 1.0f;
        else mv = ((t - 9) >= RECn - total) ? 1.0f : 0.0f;
        maskf[b * Tn + t] = mv;
    }
}

// ---------------------------------------------------------------- q = queries @ Wq^T + bq
__global__ void q_kernel(const float* __restrict__ queries,
                         const float* __restrict__ in_w,
                         const float* __restrict__ in_b,
                         float* __restrict__ q) {
    int wid = (blockIdx.x * blockDim.x + threadIdx.x) >> 6;
    int lane = threadIdx.x & 63;
    if (wid >= Pn * Dn) return;
    int p = wid >> 10, j = wid & 1023;
    float acc = 0.0f;
    for (int c = lane; c < Dn; c += 64)
        acc += queries[p * Dn + c] * in_w[(size_t)j * Dn + c];
#pragma unroll
    for (int off = 32; off > 0; off >>= 1) acc += __shfl_down(acc, off);
    if (lane == 0) q[wid] = acc + in_b[j];
}

// ---------------------------------------------------------------- A_bf[h*8+p,c] = bf16((q_h[p] . Wk_h[:,c]) / 8) ; c0
__global__ void A_kernel(const float* __restrict__ q,
                         const float* __restrict__ in_w,
                         const float* __restrict__ in_b,
                         short* __restrict__ Amat_bf, float* __restrict__ c0) {
    int h = blockIdx.x, cblk = blockIdx.y;
    int c = cblk * 256 + threadIdx.x;
    __shared__ float qs[8][64];
    for (int i = threadIdx.x; i < 512; i += 256) {
        int p = i >> 6, d = i & 63;
        qs[p][d] = q[p * Dn + h * 64 + d];
    }
    __syncthreads();
    float acc[8] = {};
#pragma unroll 8
    for (int d = 0; d < 64; d++) {
        float w = in_w[(size_t)(Dn + h * 64 + d) * Dn + c];
#pragma unroll
        for (int p = 0; p < 8; p++) acc[p] = fmaf(qs[p][d], w, acc[p]);
    }
#pragma unroll
    for (int p = 0; p < 8; p++)
        Amat_bf[(size_t)(h * 8 + p) * Dn + c] = f2bf(acc[p] * 0.125f);
    if (cblk == 0 && threadIdx.x < 8) {
        int p = threadIdx.x;
        float a = 0.0f;
        for (int d = 0; d < 64; d++) a += qs[p][d] * in_b[Dn + h * 64 + d];
        c0[h * 8 + p] = a * 0.125f;
    }
}

// ---------------------------------------------------------------- f32 -> bf16 elementwise (weights)
__global__ void wcvt_kernel(const float* __restrict__ w, short* __restrict__ wbf, int n) {
    int i = (blockIdx.x * blockDim.x + threadIdx.x) * 8;
    if (i >= n) return;
    f32x4 x0 = *(const f32x4*)(w + i);
    f32x4 x1 = *(const f32x4*)(w + i + 4);
    short8 o;
#pragma unroll
    for (int j = 0; j < 4; j++) { o[j] = f2bf(x0[j]); o[j + 4] = f2bf(x1[j]); }
    *(short8*)(wbf + i) = o;
}

// ---------------------------------------------------------------- scores[b,hp,s] = hidden[b,s,:]@A[hp,:] + c0 (MFMA bf16), masked
// 256 blocks x 512 threads (8 waves). Block = 128 s-rows x 128 hp, FULL K.
// Amat staged in ping-pong 2x64KB LDS K-quarters (6 barriers/block total);
// hidden streams through a 4-deep register prefetch ring (64KB/CU in flight).
__global__ __launch_bounds__(512) void scores_mfma(const float* __restrict__ hidden,
                                                   const short* __restrict__ Amat_bf,
                                                   const float* __restrict__ c0,
                                                   const unsigned char* __restrict__ valid,
                                                   float* __restrict__ scores) {
    __shared__ short Bsh[2][64 * 512];        // 2 x (128 hp x 256 k), swizzled
    int tid = threadIdx.x, wave = tid >> 6, lane = tid & 63;
    int l15 = lane & 15, q = lane >> 4;
    int m0 = blockIdx.x * 128 + wave * 16;
    int b = m0 >> 11, s_base = m0 & 2047;

    int sr = tid >> 2, skc = (tid & 3) * 64;  // staging: thread -> (hp row, 64-k slice)
    const short* aglob = Amat_bf + (size_t)sr * Dn + skc;

    // prologue: stage quarter 0 into buf 0
    {
#pragma unroll
        for (int j = 0; j < 8; j++) {
            short8 v = *(const short8*)(aglob + j * 8);
            *(short8*)(&Bsh[0][swzP(sr, skc + j * 8, 256)]) = v;
        }
    }
    __syncthreads();

    const float* aptr = hidden + (size_t)(m0 + l15) * Dn + q * 8;
    f32x4 acc[8] = {};
    f32x4 pa[4][2];
#pragma unroll
    for (int d = 0; d < 4; d++) {
        pa[d][0] = *(const f32x4*)(aptr + d * 32);
        pa[d][1] = *(const f32x4*)(aptr + d * 32 + 4);
    }

    for (int kq = 0; kq < 4; kq++) {
        int cur = kq & 1;
        short8 sreg[8];
        if (kq < 3) {
            const short* src = aglob + (kq + 1) * 256;
#pragma unroll
            for (int j = 0; j < 8; j++) sreg[j] = *(const short8*)(src + j * 8);
        }
#pragma unroll
        for (int icq = 0; icq < 8; icq++) {
            int ic = kq * 8 + icq;            // global chunk
            f32x4 h0 = pa[icq & 3][0], h1 = pa[icq & 3][1];
            if (ic + 4 < 32) {
                pa[icq & 3][0] = *(const f32x4*)(aptr + (ic + 4) * 32);
                pa[icq & 3][1] = *(const f32x4*)(aptr + (ic + 4) * 32 + 4);
            }
            short8 av;
#pragma unroll
            for (int i = 0; i < 4; i++) { av[i] = f2bf(h0[i]); av[i + 4] = f2bf(h1[i]); }
#pragma unroll
            for (int nt = 0; nt < 8; nt++) {
                short8 bv = *(const short8*)(&Bsh[cur][swzP(nt * 16 + l15, icq * 32 + q * 8, 256)]);
                acc[nt] = __builtin_amdgcn_mfma_f32_16x16x32_bf16(av, bv, acc[nt], 0, 0, 0);
            }
        }
        if (kq < 3) {
            __syncthreads();                  // all waves done reading buf cur^1
#pragma unroll
            for (int j = 0; j < 8; j++)
                *(short8*)(&Bsh[cur ^ 1][swzP(sr, skc + j * 8, 256)]) = sreg[j];
            __syncthreads();                  // writes visible
        }
    }

    // epilogue: C/D layout col=lane&15 (hp), row=q*4+reg (s); +c0, mask
    int srow = s_base + q * 4;
    const unsigned char* vptr = valid + (size_t)b * Sn + srow;
    bool ok0 = vptr[0] != 0, ok1 = vptr[1] != 0, ok2 = vptr[2] != 0, ok3 = vptr[3] != 0;
#pragma unroll
    for (int nt = 0; nt < 8; nt++) {
        int hp = nt * 16 + l15;
        float cc = c0[hp];
        f32x4 st;
        st[0] = ok0 ? acc[nt][0] + cc : -1.0e9f;
        st[1] = ok1 ? acc[nt][1] + cc : -1.0e9f;
        st[2] = ok2 ? acc[nt][2] + cc : -1.0e9f;
        st[3] = ok3 ? acc[nt][3] + cc : -1.0e9f;
        *(f32x4*)(scores + (size_t)(b * 128 + hp) * Sn + srow) = st;
    }
}

// ---------------------------------------------------------------- softmax over s; writes bf16 attn
__global__ __launch_bounds__(256) void softmax_kernel(const float* __restrict__ scores,
                                                      short* __restrict__ attn_bf) {
    const float* row = scores + (size_t)blockIdx.x * Sn;
    short* orow = attn_bf + (size_t)blockIdx.x * Sn;
    int t = threadIdx.x;
    __shared__ float red[256];
    f32x4 v0 = *(const f32x4*)(row + t * 8);
    f32x4 v1 = *(const f32x4*)(row + t * 8 + 4);
    float mx = -1.0e30f;
#pragma unroll
    for (int i = 0; i < 4; i++) { mx = fmaxf(mx, v0[i]); mx = fmaxf(mx, v1[i]); }
    red[t] = mx;
    __syncthreads();
    for (int off = 128; off > 0; off >>= 1) {
        if (t < off) red[t] = fmaxf(red[t], red[t + off]);
        __syncthreads();
    }
    mx = red[0];
    __syncthreads();
    float e[8];
    float sum = 0.0f;
#pragma unroll
    for (int i = 0; i < 4; i++) {
        e[i] = expf(v0[i] - mx); sum += e[i];
        e[i + 4] = expf(v1[i] - mx); sum += e[i + 4];
    }
    red[t] = sum;
    __syncthreads();
    for (int off = 128; off > 0; off >>= 1) {
        if (t < off) red[t] += red[t + off];
        __syncthreads();
    }
    float inv = 1.0f / red[0];
    short8 o;
#pragma unroll
    for (int i = 0; i < 8; i++) o[i] = f2bf(e[i] * inv);
    *(short8*)(orow + t * 8) = o;
}

// ---------------------------------------------------------------- U partials: Up[b,hp,c] = sum_{s in z-chunk} attn[b,hp,s]*hidden[b,s,c]
// grid (16 c-tiles of 64, 16 b, 4 z) x 512 threads. LDS 64KB (2 blocks/CU,
// 16 waves/CU). Hidden z-chunk staged transposed ONCE; attn streams with
// 4-deep prefetch; barrier-free main loop.
__global__ __launch_bounds__(512) void U_mfma(const short* __restrict__ attn_bf,
                                              const float* __restrict__ hidden,
                                              float* __restrict__ Up0,
                                              float* __restrict__ Up1,
                                              float* __restrict__ Up2,
                                              float* __restrict__ Up3) {
    __shared__ short Hs[64 * 512];            // 64 c x 512 s, swizzled
    int n0 = blockIdx.x * 64, b = blockIdx.y, z = blockIdx.z;
    int zbase = z * 512;
    float* Up = (z == 0) ? Up0 : (z == 1) ? Up1 : (z == 2) ? Up2 : Up3;
    int tid = threadIdx.x, wave = tid >> 6, lane = tid & 63;
    int l15 = lane & 15, q = lane >> 4;

    // stage: thread t owns s-row = tid; transpose-write 64 c values
    {
        const float* src = hidden + ((size_t)b * Sn + zbase + tid) * Dn + n0;
#pragma unroll
        for (int c8 = 0; c8 < 64; c8 += 8) {
            f32x4 x = *(const f32x4*)(src + c8);
            f32x4 y = *(const f32x4*)(src + c8 + 4);
#pragma unroll
            for (int i = 0; i < 4; i++) {
                int c = c8 + i;
                Hs[c * 512 + (tid ^ ((c & 7) << 3))] = f2bf(x[i]);
            }
#pragma unroll
            for (int i = 0; i < 4; i++) {
                int c = c8 + 4 + i;
                Hs[c * 512 + (tid ^ ((c & 7) << 3))] = f2bf(y[i]);
            }
        }
    }
    __syncthreads();                          // the only barrier

    const short* ap = attn_bf + ((size_t)b * 128 + wave * 16 + l15) * Sn + zbase + q * 8;
    f32x4 acc[4] = {};
    short8 pa4[4];
#pragma unroll
    for (int d = 0; d < 4; d++) pa4[d] = *(const short8*)(ap + d * 32);
#pragma unroll
    for (int ic = 0; ic < 16; ic++) {
        short8 av = pa4[ic & 3];
        if (ic + 4 < 16) pa4[ic & 3] = *(const short8*)(ap + (ic + 4) * 32);
#pragma unroll
        for (int nf = 0; nf < 4; nf++) {
            short8 bv = *(const short8*)(&Hs[swzP(nf * 16 + l15, ic * 32 + q * 8, 512)]);
            acc[nf] = __builtin_amdgcn_mfma_f32_16x16x32_bf16(av, bv, acc[nf], 0, 0, 0);
        }
    }
    int hp = wave * 16 + q * 4;
#pragma unroll
    for (int nf = 0; nf < 4; nf++) {
        int c = n0 + nf * 16 + l15;
        float* up = Up + (size_t)(b * 128 + hp) * Dn + c;
#pragma unroll
        for (int r = 0; r < 4; r++) up[(size_t)r * Dn] = acc[nf][r];
    }
}

// ---------------------------------------------------------------- ctx[bp, h*64+d] = (sum Up)[b,h*8+p,:] . Wv[h*64+d,:] + bv  (MFMA)
__global__ __launch_bounds__(64) void ctx_mfma(const float* __restrict__ Up0,
                                               const float* __restrict__ Up1,
                                               const float* __restrict__ Up2,
                                               const float* __restrict__ Up3,
                                               const float* __restrict__ in_w,
                                               const float* __restrict__ in_b,
                                               float* __restrict__ ctx) {
    int bh = blockIdx.x, b = bh >> 4, h = bh & 15;
    int lane = threadIdx.x & 63, l15 = lane & 15, koff = (lane >> 4) * 8;
    int p = l15 & 7;
    size_t uoff = ((size_t)b * 128 + h * 8 + p) * Dn + koff;
    const float* wv = in_w + (size_t)(2 * Dn + h * 64 + l15) * Dn + koff;
    f32x4 acc[4] = {};
    for (int k0 = 0; k0 < Dn; k0 += 32) {
        f32x4 a0 = *(const f32x4*)(Up0 + uoff + k0);
        f32x4 a1 = *(const f32x4*)(Up0 + uoff + k0 + 4);
        f32x4 b0 = *(const f32x4*)(Up1 + uoff + k0);
        f32x4 b1 = *(const f32x4*)(Up1 + uoff + k0 + 4);
        f32x4 d0 = *(const f32x4*)(Up2 + uoff + k0);
        f32x4 d1 = *(const f32x4*)(Up2 + uoff + k0 + 4);
        f32x4 e0 = *(const f32x4*)(Up3 + uoff + k0);
        f32x4 e1 = *(const f32x4*)(Up3 + uoff + k0 + 4);
        short8 av;
#pragma unroll
        for (int i = 0; i < 4; i++) {
            av[i] = f2bf((a0[i] + b0[i]) + (d0[i] + e0[i]));
            av[i + 4] = f2bf((a1[i] + b1[i]) + (d1[i] + e1[i]));
        }
#pragma unroll
        for (int nt = 0; nt < 4; nt++) {
            f32x4 w0 = *(const f32x4*)(wv + (size_t)nt * 16 * Dn + k0);
            f32x4 w1 = *(const f32x4*)(wv + (size_t)nt * 16 * Dn + k0 + 4);
            short8 bv;
#pragma unroll
            for (int i = 0; i < 4; i++) { bv[i] = f2bf(w0[i]); bv[i + 4] = f2bf(w1[i]); }
            acc[nt] = __builtin_amdgcn_mfma_f32_16x16x32_bf16(av, bv, acc[nt], 0, 0, 0);
        }
    }
    if (lane < 32) {                          // rows 0-7 valid (p)
        int prow = (lane >> 4) * 4;
#pragma unroll
        for (int nt = 0; nt < 4; nt++) {
            int d = h * 64 + nt * 16 + l15;
            float bias = in_b[2 * Dn + d];
#pragma unroll
            for (int r = 0; r < 4; r++)
                ctx[(size_t)(b * 8 + prow + r) * Dn + d] = acc[nt][r] + bias;
        }
    }
}

// ---------------------------------------------------------------- pooled = ctx @ out_w^T + out_b (MFMA, f32 operands cvt in-reg)
__global__ __launch_bounds__(256) void pooled_mfma(const float* __restrict__ A,
                                                   const float* __restrict__ B,
                                                   const float* __restrict__ bias,
                                                   float* __restrict__ C, int M) {
    int wave = threadIdx.x >> 6, lane = threadIdx.x & 63;
    int l15 = lane & 15, koff = (lane >> 4) * 8;
    int m0 = blockIdx.x * 64 + (wave >> 1) * 32;
    int n0 = blockIdx.y * 64 + (wave & 1) * 32;
    f32x4 acc[2][2] = {};
    int ra0 = min(m0 + l15, M - 1);
    int ra1 = min(m0 + 16 + l15, M - 1);
    const float* a0p = A + (size_t)ra0 * Dn + koff;
    const float* a1p = A + (size_t)ra1 * Dn + koff;
    const float* b0p = B + (size_t)(n0 + l15) * Dn + koff;
    const float* b1p = B + (size_t)(n0 + 16 + l15) * Dn + koff;
    for (int k0 = 0; k0 < Dn; k0 += 32) {
        short8 av0, av1, bv0, bv1;
        f32x4 x, y;
        x = *(const f32x4*)(a0p + k0); y = *(const f32x4*)(a0p + k0 + 4);
#pragma unroll
        for (int i = 0; i < 4; i++) { av0[i] = f2bf(x[i]); av0[i + 4] = f2bf(y[i]); }
        x = *(const f32x4*)(a1p + k0); y = *(const f32x4*)(a1p + k0 + 4);
#pragma unroll
        for (int i = 0; i < 4; i++) { av1[i] = f2bf(x[i]); av1[i + 4] = f2bf(y[i]); }
        x = *(const f32x4*)(b0p + k0); y = *(const f32x4*)(b0p + k0 + 4);
#pragma unroll
        for (int i = 0; i < 4; i++) { bv0[i] = f2bf(x[i]); bv0[i + 4] = f2bf(y[i]); }
        x = *(const f32x4*)(b1p + k0); y = *(const f32x4*)(b1p + k0 + 4);
#pragma unroll
        for (int i = 0; i < 4; i++) { bv1[i] = f2bf(x[i]); bv1[i + 4] = f2bf(y[i]); }
        acc[0][0] = __builtin_amdgcn_mfma_f32_16x16x32_bf16(av0, bv0, acc[0][0], 0, 0, 0);
        acc[0][1] = __builtin_amdgcn_mfma_f32_16x16x32_bf16(av0, bv1, acc[0][1], 0, 0, 0);
        acc[1][0] = __builtin_amdgcn_mfma_f32_16x16x32_bf16(av1, bv0, acc[1][0], 0, 0, 0);
        acc[1][1] = __builtin_amdgcn_mfma_f32_16x16x32_bf16(av1, bv1, acc[1][1], 0, 0, 0);
    }
#pragma unroll
    for (int mf = 0; mf < 2; mf++) {
        int row0 = m0 + mf * 16 + (lane >> 4) * 4;
#pragma unroll
        for (int nf = 0; nf < 2; nf++) {
            int col = n0 + nf * 16 + l15;
            float bval = bias[col];
#pragma unroll
            for (int r = 0; r < 4; r++) {
                int row = row0 + r;
                if (row < M) C[(size_t)row * Dn + col] = acc[mf][nf][r] + bval;
            }
        }
    }
}

// ---------------------------------------------------------------- bf16 MFMA GEMM: C[M,1024] = A_bf[M,1024] @ B_bf[1024,1024]^T + bias
__global__ __launch_bounds__(256) void wgemm_mfma(const short* __restrict__ Abf,
                                                  const short* __restrict__ Bbf,
                                                  const float* __restrict__ bias,
                                                  float* __restrict__ C, int M) {
    int wave = threadIdx.x >> 6, lane = threadIdx.x & 63;
    int m0 = blockIdx.x * 64 + (wave >> 1) * 32;
    int n0 = blockIdx.y * 64 + (wave & 1) * 32;
    int koff = (lane >> 4) * 8;
    f32x4 acc[2][2] = {};
    int ra0 = min(m0 + (lane & 15), M - 1);
    int ra1 = min(m0 + 16 + (lane & 15), M - 1);
    const short* a0p = Abf + (size_t)ra0 * Dn + koff;
    const short* a1p = Abf + (size_t)ra1 * Dn + koff;
    const short* b0p = Bbf + (size_t)(n0 + (lane & 15)) * Dn + koff;
    const short* b1p = Bbf + (size_t)(n0 + 16 + (lane & 15)) * Dn + koff;
    for (int k0 = 0; k0 < Dn; k0 += 32) {
        short8 av0 = *(const short8*)(a0p + k0);
        short8 av1 = *(const short8*)(a1p + k0);
        short8 bv0 = *(const short8*)(b0p + k0);
        short8 bv1 = *(const short8*)(b1p + k0);
        acc[0][0] = __builtin_amdgcn_mfma_f32_16x16x32_bf16(av0, bv0, acc[0][0], 0, 0, 0);
        acc[0][1] = __builtin_amdgcn_mfma_f32_16x16x32_bf16(av0, bv1, acc[0][1], 0, 0, 0);
        acc[1][0] = __builtin_amdgcn_mfma_f32_16x16x32_bf16(av1, bv0, acc[1][0], 0, 0, 0);
        acc[1][1] = __builtin_amdgcn_mfma_f32_16x16x32_bf16(av1, bv1, acc[1][1], 0, 0, 0);
    }
#pragma unroll
    for (int mf = 0; mf < 2; mf++) {
        int row0 = m0 + mf * 16 + (lane >> 4) * 4;
#pragma unroll
        for (int nf = 0; nf < 2; nf++) {
            int col = n0 + nf * 16 + (lane & 15);
            float bval = bias[col];
#pragma unroll
            for (int r = 0; r < 4; r++) {
                int row = row0 + r;
                if (row < M) C[(size_t)row * Dn + col] = acc[mf][nf][r] + bval;
            }
        }
    }
}

// ---------------------------------------------------------------- block sum helper
__device__ __forceinline__ float block_sum(float v, float* red) {
    int tid = threadIdx.x;
    red[tid] = v;
    __syncthreads();
    for (int off = 128; off > 0; off >>= 1) {
        if (tid < off) red[tid] += red[tid + off];
        __syncthreads();
    }
    float r = red[0];
    __syncthreads();
    return r;
}

// ---------------------------------------------------------------- build summary row + LN_pma + LN_v / LN_g (bf16 out)
__global__ void summary_ln_kernel(const float* __restrict__ hidden,
                                  const float* __restrict__ queries,
                                  const float* __restrict__ pooled,
                                  const int* __restrict__ rsrc,
                                  const float* __restrict__ gpma, const float* __restrict__ bpma,
                                  const float* __restrict__ gv, const float* __restrict__ bv,
                                  const float* __restrict__ gg, const float* __restrict__ bg,
                                  short* __restrict__ lnv, short* __restrict__ lng) {
    __shared__ float red[256];
    int b = blockIdx.x, t = blockIdx.y, tid = threadIdx.x;
    float x[4];
    if (t == 0) {
#pragma unroll
        for (int i = 0; i < 4; i++)
            x[i] = hidden[(size_t)b * Sn * Dn + tid + i * 256];
    } else if (t < 1 + Pn) {
        int p = t - 1;
#pragma unroll
        for (int i = 0; i < 4; i++) {
            int c = tid + i * 256;
            x[i] = queries[p * Dn + c] + pooled[((size_t)b * Pn + p) * Dn + c];
        }
    } else {
        int src = rsrc[b * RECn + (t - 9)];
        if (src >= 0) {
#pragma unroll
            for (int i = 0; i < 4; i++)
                x[i] = hidden[((size_t)b * Sn + src) * Dn + tid + i * 256];
        } else {
#pragma unroll
            for (int i = 0; i < 4; i++) x[i] = 0.0f;
        }
    }
    if (t >= 1 && t < 1 + Pn) {
        float mu = block_sum(x[0] + x[1] + x[2] + x[3], red) * (1.0f / Dn);
        float d2 = 0.0f;
#pragma unroll
        for (int i = 0; i < 4; i++) { float d = x[i] - mu; d2 += d * d; }
        float inv = rsqrtf(block_sum(d2, red) * (1.0f / Dn) + 1e-5f);
#pragma unroll
        for (int i = 0; i < 4; i++) {
            int c = tid + i * 256;
            x[i] = (x[i] - mu) * inv * gpma[c] + bpma[c];
        }
    }
    float mu = block_sum(x[0] + x[1] + x[2] + x[3], red) * (1.0f / Dn);
    float d2 = 0.0f;
#pragma unroll
    for (int i = 0; i < 4; i++) { float d = x[i] - mu; d2 += d * d; }
    float inv = rsqrtf(block_sum(d2, red) * (1.0f / Dn) + 1e-5f);
    size_t row = (size_t)(b * Tn + t) * Dn;
#pragma unroll
    for (int i = 0; i < 4; i++) {
        int c = tid + i * 256;
        float xh = (x[i] - mu) * inv;
        lnv[row + c] = f2bf(xh * gv[c] + bv[c]);
        lng[row + c] = f2bf(xh * gg[c] + bg[c]);
    }
}

// ---------------------------------------------------------------- gated = sigmoid(c2) * silu(c1) * mask
__global__ void gated_kernel(const float* __restrict__ c1, const float* __restrict__ c2,
                             const float* __restrict__ maskf, float* __restrict__ out) {
    int gi = blockIdx.x * blockDim.x + threadIdx.x;
    int row = gi >> 10;
    float m = maskf[row];
    float a = c1[gi], g = c2[gi];
    float sv = a / (1.0f + expf(-a));
    float sg = 1.0f / (1.0f + expf(-g));
    out[gi] = sg * sv * m;
}

// ================================================================ launch
extern "C" void kernel_launch(void* const* d_in, const int* in_sizes, int n_in,
                              void* d_out, int out_size, void* d_ws, size_t ws_size,
                              hipStream_t stream) {
    const float* hidden = (const float*)d_in[0];
    const void* valid_raw = d_in[1];
    const float* queries = (const float*)d_in[2];
    const float* in_w = (const float*)d_in[3];
    const float* in_b = (const float*)d_in[4];
    const float* out_w = (const float*)d_in[5];
    const float* out_b = (const float*)d_in[6];
    const float* ln_pma_g = (const float*)d_in[7];
    const float* ln_pma_b = (const float*)d_in[8];
    const float* ln_v_g = (const float*)d_in[9];
    const float* ln_v_b = (const float*)d_in[10];
    const float* W_v = (const float*)d_in[11];
    const float* b_v = (const float*)d_in[12];
    const float* ln_g_g = (const float*)d_in[13];
    const float* ln_g_b = (const float*)d_in[14];
    const float* W_g = (const float*)d_in[15];
    const float* b_g = (const float*)d_in[16];

    float* ws = (float*)d_ws;
    float* out = (float*)d_out;

    // workspace layout (float offsets):
    float* SC      = ws;                         // scores f32: 4,194,304 f (dead after softmax)
    short* attn_bf = (short*)(ws + 4194304);     // 4,194,304 shorts = 2,097,152 f
    float* Up0     = ws;                         // overlay dead SC region
    float* Up1     = ws + 2097152;               // overlay dead SC region
    float* Up2     = ws + 6291456;               // 2,097,152 f
    float* Up3     = ws + 8388608;               // 2,097,152 f (ends 10,485,760)
    float* qbuf    = ws + 10485760;              // 8,192
    short* Amat_bf = (short*)(ws + 10493952);    // 65,536 f
    float* c0      = ws + 10559488;              // 256
    float* ctx     = ws + 10559744;              // 131,072
    float* pooled  = ws + 10690816;              // 131,072
    short* Wv_bf   = (short*)(ws + 10821888);    // 524,288 f
    short* Wg_bf   = (short*)(ws + 11346176);    // 524,288 f
    int*   ivals   = (int*)(ws + 11870464);
    int* totals = ivals;                         // 16
    int* rsrc = ivals + 16;                      // 1024
    int* flag = ivals + 16 + 1024;               // 16
    unsigned char* canon = (unsigned char*)(ivals + 16 + 1024 + 16); // 32768 B
    // post-ctx overlays (Up0..3 dead after ctx):
    short* lnv_bf = (short*)ws;
    short* lng_bf = (short*)(ws + 622592);
    float* c1 = ws + 1245184;
    float* c2 = ws + 2441216;                    // ends 3,637,248 OK
    float* maskf = out + (size_t)Bn * Tn * Dn;

    const int M2 = Bn * Tn; // 1168

    detect_mask_kernel<<<1, 256, 0, stream>>>((const unsigned char*)valid_raw, flag);
    canon_mask_kernel<<<(Bn * Sn) / 256, 256, 0, stream>>>(valid_raw, flag, canon);
    prep_kernel<<<Bn, 256, 0, stream>>>(canon, totals, rsrc, maskf);
    q_kernel<<<(Pn * Dn) / 4, 256, 0, stream>>>(queries, in_w, in_b, qbuf);
    A_kernel<<<dim3(Hn, 4), 256, 0, stream>>>(qbuf, in_w, in_b, Amat_bf, c0);
    wcvt_kernel<<<512, 256, 0, stream>>>(W_v, Wv_bf, Dn * Dn);
    wcvt_kernel<<<512, 256, 0, stream>>>(W_g, Wg_bf, Dn * Dn);
    scores_mfma<<<(Bn * Sn) / 128, 512, 0, stream>>>(hidden, Amat_bf, c0, canon, SC);
    softmax_kernel<<<Bn * 128, 256, 0, stream>>>(SC, attn_bf);
    U_mfma<<<dim3(16, Bn, 4), 512, 0, stream>>>(attn_bf, hidden, Up0, Up1, Up2, Up3);
    ctx_mfma<<<Bn * Hn, 64, 0, stream>>>(Up0, Up1, Up2, Up3, in_w, in_b, ctx);
    pooled_mfma<<<dim3(2, 16), 256, 0, stream>>>(ctx, out_w, out_b, pooled, Bn * Pn);
    summary_ln_kernel<<<dim3(Bn, Tn), 256, 0, stream>>>(hidden, queries, pooled, rsrc,
                                                        ln_pma_g, ln_pma_b, ln_v_g, ln_v_b,
                                                        ln_g_g, ln_g_b, lnv_bf, lng_bf);
    wgemm_mfma<<<dim3((M2 + 63) / 64, 16), 256, 0, stream>>>(lnv_bf, Wv_bf, b_v, c1, M2);
    wgemm_mfma<<<dim3((M2 + 63) / 64, 16), 256, 0, stream>>>(lng_bf, Wg_bf, b_g, c2, M2);
    gated_kernel<<<(Bn * Tn * Dn) / 256, 256, 0, stream>>>(c1, c2, maskf, out);
}

// Round 10
// 249.311 us; speedup vs baseline: 1.0191x; 1.0191x over previous
//
#include <hip/hip_runtime.h>
#include <hip/hip_bf16.h>
#include <math.h>

// Dims fixed by setup_inputs(): B=16, S=2048, D=1024, H=16, hd=64, P=8,
// cls=1, pma=8, recent=64, T=73.

#define Bn 16
#define Sn 2048
#define Dn 1024
#define Hn 16
#define Pn 8
#define Tn 73
#define RECn 64

typedef __attribute__((ext_vector_type(8))) short short8;
typedef __attribute__((ext_vector_type(4))) float f32x4;

__device__ __forceinline__ short f2bf(float x) {
    union { __hip_bfloat16 h; short s; } u;
    u.h = __float2bfloat16(x);   // native v_cvt, RNE
    return u.s;
}

// async global->LDS DMA, 16B per lane. LDS dest is wave-uniform base+lane*16;
// global src is per-lane (swizzle goes on the SOURCE, LDS stays linear).
__device__ __forceinline__ void gload_lds16(const void* g, void* l) {
    __builtin_amdgcn_global_load_lds((const __attribute__((address_space(1))) void*)g,
                                     (__attribute__((address_space(3))) void*)l, 16, 0, 0);
}

// XOR swizzle: spreads row r's 16B slots across bank groups (U_mfma staging).
__device__ __forceinline__ int swzP(int row, int ks, int pitch) {
    return row * pitch + (ks ^ ((row & 7) << 3));
}

// ---------------------------------------------------------------- mask dtype detect
__global__ void detect_mask_kernel(const unsigned char* __restrict__ raw,
                                   int* __restrict__ flag) {
    __shared__ int any;
    if (threadIdx.x == 0) any = 0;
    __syncthreads();
    const uint4* r4 = (const uint4*)raw;
    int local = 0;
    for (int i = threadIdx.x; i < (Bn * Sn) / 16; i += blockDim.x) {
        uint4 w = r4[i];
        if ((w.x & 0xFFFFFF00u) | (w.y & 0xFFFFFF00u) |
            (w.z & 0xFFFFFF00u) | (w.w & 0xFFFFFF00u)) local = 1;
    }
    if (local) any = 1; // benign race
    __syncthreads();
    if (threadIdx.x == 0) *flag = any;
}

__global__ void canon_mask_kernel(const void* __restrict__ raw,
                                  const int* __restrict__ flag,
                                  unsigned char* __restrict__ canon) {
    int i = blockIdx.x * blockDim.x + threadIdx.x;
    if (i >= Bn * Sn) return;
    unsigned char v;
    if (*flag)
        v = ((const unsigned char*)raw)[i] ? 1 : 0;
    else
        v = ((const int*)raw)[i] ? 1 : 0;
    canon[i] = v;
}

// ---------------------------------------------------------------- prep
__global__ void prep_kernel(const unsigned char* __restrict__ valid,
                            int* __restrict__ totals, int* __restrict__ rsrc,
                            float* __restrict__ maskf) {
    int b = blockIdx.x, t = threadIdx.x;
    const int SP = Sn - 1; // 2047
    __shared__ int lc[256];
    if (t < RECn) rsrc[b * RECn + t] = -1;

    int base = t * 8;
    unsigned char m[8];
    int cnt = 0;
#pragma unroll
    for (int i = 0; i < 8; i++) {
        int idx = base + i;
        m[i] = (idx < SP) ? valid[(size_t)b * Sn + 1 + idx] : (unsigned char)0;
        cnt += m[i] ? 1 : 0;
    }
    lc[t] = cnt;
    __syncthreads();
    for (int off = 1; off < 256; off <<= 1) {
        int add = (t >= off) ? lc[t - off] : 0;
        __syncthreads();
        lc[t] += add;
        __syncthreads();
    }
    int total = lc[255];
    int run = lc[t] - cnt; // exclusive prefix
#pragma unroll
    for (int i = 0; i < 8; i++) {
        if (m[i]) {
            run++;
            int rank = total - run;
            if (rank < RECn) rsrc[b * RECn + (RECn - 1 - rank)] = base + i + 1;
        }
    }
    if (t == 0) totals[b] = total;
    if (t < Tn) {
        float mv;
        if (t == 0) mv = valid[(size_t)b * Sn] ? 1.0f : 0.0f;
        else if (t < 1 + Pn) mv = 1.0f;
        else mv = ((t - 9) >= RECn - total) ? 1.0f : 0.0f;
        maskf[b * Tn + t] = mv;
    }
}

// ---------------------------------------------------------------- q = queries @ Wq^T + bq
__global__ void q_kernel(const float* __restrict__ queries,
                         const float* __restrict__ in_w,
                         const float* __restrict__ in_b,
                         float* __restrict__ q) {
    int wid = (blockIdx.x * blockDim.x + threadIdx.x) >> 6;
    int lane = threadIdx.x & 63;
    if (wid >= Pn * Dn) return;
    int p = wid >> 10, j = wid & 1023;
    float acc = 0.0f;
    for (int c = lane; c < Dn; c += 64)
        acc += queries[p * Dn + c] * in_w[(size_t)j * Dn + c];
#pragma unroll
    for (int off = 32; off > 0; off >>= 1) acc += __shfl_down(acc, off);
    if (lane == 0) q[wid] = acc + in_b[j];
}

// ---------------------------------------------------------------- A_bf[h*8+p,c] = bf16((q_h[p] . Wk_h[:,c]) / 8) ; c0
__global__ void A_kernel(const float* __restrict__ q,
                         const float* __restrict__ in_w,
                         const float* __restrict__ in_b,
                         short* __restrict__ Amat_bf, float* __restrict__ c0) {
    int h = blockIdx.x, cblk = blockIdx.y;
    int c = cblk * 256 + threadIdx.x;
    __shared__ float qs[8][64];
    for (int i = threadIdx.x; i < 512; i += 256) {
        int p = i >> 6, d = i & 63;
        qs[p][d] = q[p * Dn + h * 64 + d];
    }
    __syncthreads();
    float acc[8] = {};
#pragma unroll 8
    for (int d = 0; d < 64; d++) {
        float w = in_w[(size_t)(Dn + h * 64 + d) * Dn + c];
#pragma unroll
        for (int p = 0; p < 8; p++) acc[p] = fmaf(qs[p][d], w, acc[p]);
    }
#pragma unroll
    for (int p = 0; p < 8; p++)
        Amat_bf[(size_t)(h * 8 + p) * Dn + c] = f2bf(acc[p] * 0.125f);
    if (cblk == 0 && threadIdx.x < 8) {
        int p = threadIdx.x;
        float a = 0.0f;
        for (int d = 0; d < 64; d++) a += qs[p][d] * in_b[Dn + h * 64 + d];
        c0[h * 8 + p] = a * 0.125f;
    }
}

// ---------------------------------------------------------------- f32 -> bf16 elementwise (weights)
__global__ void wcvt_kernel(const float* __restrict__ w, short* __restrict__ wbf, int n) {
    int i = (blockIdx.x * blockDim.x + threadIdx.x) * 8;
    if (i >= n) return;
    f32x4 x0 = *(const f32x4*)(w + i);
    f32x4 x1 = *(const f32x4*)(w + i + 4);
    short8 o;
#pragma unroll
    for (int j = 0; j < 4; j++) { o[j] = f2bf(x0[j]); o[j + 4] = f2bf(x1[j]); }
    *(short8*)(wbf + i) = o;
}

// ---------------------------------------------------------------- scores[b,hp,s] = hidden[b,s,:]@A[hp,:] + c0 (MFMA bf16), masked
// m97-replica: 512 blocks x 256 thr (4 waves). Tile 64 s x 128 hp, BK=32.
// Both operands staged via global_load_lds(16B) into double-buffered LDS
// (32 KB total), one barrier per K-step. Source-address swizzle gives 2-way
// (free) bank access on all ds_reads. Wave w: s-half ws=w>>1, hp-half wh=w&1.
__global__ __launch_bounds__(256) void scores_mfma(const float* __restrict__ hidden,
                                                   const short* __restrict__ Amat_bf,
                                                   const float* __restrict__ c0,
                                                   const unsigned char* __restrict__ valid,
                                                   float* __restrict__ scores) {
    __shared__ float Af[2][64 * 32];          // A: slot16B = s*8 + (j ^ (s&7))
    __shared__ short Bs[2][128 * 32];         // B: slot16B = hp*4 + (q ^ ((hp>>1)&3))
    int tid = threadIdx.x, wave = tid >> 6, lane = tid & 63;
    int l15 = lane & 15, q = lane >> 4;
    int m0 = blockIdx.x * 64;
    int b = m0 >> 11, s_base = m0 & 2047;
    int ws = wave >> 1, wh = wave & 1;
    int s0 = ws * 32, hp0 = wh * 64;

    auto stage = [&](int bb, int k0) {
#pragma unroll
        for (int u = 0; u < 2; u++) {         // A: 512 slots of 16B
            int i = tid + u * 256;
            int s = i >> 3, j = (i & 7) ^ (s & 7);
            gload_lds16(hidden + (size_t)(m0 + s) * Dn + k0 + j * 4, &Af[bb][i * 4]);
        }
#pragma unroll
        for (int u = 0; u < 2; u++) {         // B: 512 slots of 16B
            int i = tid + u * 256;
            int hp = i >> 2, qq = (i & 3) ^ ((hp >> 1) & 3);
            gload_lds16(Amat_bf + (size_t)hp * Dn + k0 + qq * 8, &Bs[bb][i * 8]);
        }
    };

    f32x4 acc[2][4] = {};
    stage(0, 0);
    __syncthreads();                          // drains the DMA (vmcnt 0)

    for (int t = 0; t < 32; t++) {
        int bb = t & 1;
        if (t + 1 < 32) stage(bb ^ 1, (t + 1) * 32);
        short8 av[2], bv[4];
#pragma unroll
        for (int f = 0; f < 2; f++) {
            int s = s0 + f * 16 + l15;
            int base = s * 8;
            f32x4 lo = *(const f32x4*)&Af[bb][(base + ((2 * q) ^ (s & 7))) * 4];
            f32x4 hi = *(const f32x4*)&Af[bb][(base + ((2 * q + 1) ^ (s & 7))) * 4];
#pragma unroll
            for (int i = 0; i < 4; i++) { av[f][i] = f2bf(lo[i]); av[f][i + 4] = f2bf(hi[i]); }
        }
#pragma unroll
        for (int f = 0; f < 4; f++) {
            int hp = hp0 + f * 16 + l15;
            bv[f] = *(const short8*)&Bs[bb][(hp * 4 + (q ^ ((hp >> 1) & 3))) * 8];
        }
#pragma unroll
        for (int fa = 0; fa < 2; fa++)
#pragma unroll
            for (int fb = 0; fb < 4; fb++)
                acc[fa][fb] = __builtin_amdgcn_mfma_f32_16x16x32_bf16(av[fa], bv[fb], acc[fa][fb], 0, 0, 0);
        __syncthreads();                      // one barrier per K-step (m97)
    }

    // epilogue: C/D layout col=lane&15 (hp), row=q*4+reg (s); +c0, mask
#pragma unroll
    for (int fa = 0; fa < 2; fa++) {
        int srow = s_base + s0 + fa * 16 + q * 4;
        const unsigned char* vptr = valid + (size_t)b * Sn + srow;
        bool ok0 = vptr[0] != 0, ok1 = vptr[1] != 0, ok2 = vptr[2] != 0, ok3 = vptr[3] != 0;
#pragma unroll
        for (int fb = 0; fb < 4; fb++) {
            int hp = hp0 + fb * 16 + l15;
            float cc = c0[hp];
            f32x4 st;
            st[0] = ok0 ? acc[fa][fb][0] + cc : -1.0e9f;
            st[1] = ok1 ? acc[fa][fb][1] + cc : -1.0e9f;
            st[2] = ok2 ? acc[fa][fb][2] + cc : -1.0e9f;
            st[3] = ok3 ? acc[fa][fb][3] + cc : -1.0e9f;
            *(f32x4*)(scores + (size_t)(b * 128 + hp) * Sn + srow) = st;
        }
    }
}

// ---------------------------------------------------------------- softmax over s; writes bf16 attn
__global__ __launch_bounds__(256) void softmax_kernel(const float* __restrict__ scores,
                                                      short* __restrict__ attn_bf) {
    const float* row = scores + (size_t)blockIdx.x * Sn;
    short* orow = attn_bf + (size_t)blockIdx.x * Sn;
    int t = threadIdx.x;
    __shared__ float red[256];
    f32x4 v0 = *(const f32x4*)(row + t * 8);
    f32x4 v1 = *(const f32x4*)(row + t * 8 + 4);
    float mx = -1.0e30f;
#pragma unroll
    for (int i = 0; i < 4; i++) { mx = fmaxf(mx, v0[i]); mx = fmaxf(mx, v1[i]); }
    red[t] = mx;
    __syncthreads();
    for (int off = 128; off > 0; off >>= 1) {
        if (t < off) red[t] = fmaxf(red[t], red[t + off]);
        __syncthreads();
    }
    mx = red[0];
    __syncthreads();
    float e[8];
    float sum = 0.0f;
#pragma unroll
    for (int i = 0; i < 4; i++) {
        e[i] = expf(v0[i] - mx); sum += e[i];
        e[i + 4] = expf(v1[i] - mx); sum += e[i + 4];
    }
    red[t] = sum;
    __syncthreads();
    for (int off = 128; off > 0; off >>= 1) {
        if (t < off) red[t] += red[t + off];
        __syncthreads();
    }
    float inv = 1.0f / red[0];
    short8 o;
#pragma unroll
    for (int i = 0; i < 8; i++) o[i] = f2bf(e[i] * inv);
    *(short8*)(orow + t * 8) = o;
}

// ---------------------------------------------------------------- U partials: Up[b,hp,c] = sum_{s in z-chunk} attn[b,hp,s]*hidden[b,s,c]
// grid (16 c-tiles of 64, 16 b, 4 z) x 512 threads. LDS 64KB (2 blocks/CU).
// Hidden z-chunk staged transposed ONCE; attn streams with 4-deep prefetch.
__global__ __launch_bounds__(512) void U_mfma(const short* __restrict__ attn_bf,
                                              const float* __restrict__ hidden,
                                              float* __restrict__ Up0,
                                              float* __restrict__ Up1,
                                              float* __restrict__ Up2,
                                              float* __restrict__ Up3) {
    __shared__ short Hs[64 * 512];            // 64 c x 512 s, swizzled
    int n0 = blockIdx.x * 64, b = blockIdx.y, z = blockIdx.z;
    int zbase = z * 512;
    float* Up = (z == 0) ? Up0 : (z == 1) ? Up1 : (z == 2) ? Up2 : Up3;
    int tid = threadIdx.x, wave = tid >> 6, lane = tid & 63;
    int l15 = lane & 15, q = lane >> 4;

    // stage: thread t owns s-row = tid; transpose-write 64 c values
    {
        const float* src = hidden + ((size_t)b * Sn + zbase + tid) * Dn + n0;
#pragma unroll
        for (int c8 = 0; c8 < 64; c8 += 8) {
            f32x4 x = *(const f32x4*)(src + c8);
            f32x4 y = *(const f32x4*)(src + c8 + 4);
#pragma unroll
            for (int i = 0; i < 4; i++) {
                int c = c8 + i;
                Hs[c * 512 + (tid ^ ((c & 7) << 3))] = f2bf(x[i]);
            }
#pragma unroll
            for (int i = 0; i < 4; i++) {
                int c = c8 + 4 + i;
                Hs[c * 512 + (tid ^ ((c & 7) << 3))] = f2bf(y[i]);
            }
        }
    }
    __syncthreads();                          // the only barrier

    const short* ap = attn_bf + ((size_t)b * 128 + wave * 16 + l15) * Sn + zbase + q * 8;
    f32x4 acc[4] = {};
    short8 pa4[4];
#pragma unroll
    for (int d = 0; d < 4; d++) pa4[d] = *(const short8*)(ap + d * 32);
#pragma unroll
    for (int ic = 0; ic < 16; ic++) {
        short8 av = pa4[ic & 3];
        if (ic + 4 < 16) pa4[ic & 3] = *(const short8*)(ap + (ic + 4) * 32);
#pragma unroll
        for (int nf = 0; nf < 4; nf++) {
            short8 bv = *(const short8*)(&Hs[swzP(nf * 16 + l15, ic * 32 + q * 8, 512)]);
            acc[nf] = __builtin_amdgcn_mfma_f32_16x16x32_bf16(av, bv, acc[nf], 0, 0, 0);
        }
    }
    int hp = wave * 16 + q * 4;
#pragma unroll
    for (int nf = 0; nf < 4; nf++) {
        int c = n0 + nf * 16 + l15;
        float* up = Up + (size_t)(b * 128 + hp) * Dn + c;
#pragma unroll
        for (int r = 0; r < 4; r++) up[(size_t)r * Dn] = acc[nf][r];
    }
}

// ---------------------------------------------------------------- ctx[bp, h*64+d] = (sum Up)[b,h*8+p,:] . Wv[h*64+d,:] + bv  (MFMA)
__global__ __launch_bounds__(64) void ctx_mfma(const float* __restrict__ Up0,
                                               const float* __restrict__ Up1,
                                               const float* __restrict__ Up2,
                                               const float* __restrict__ Up3,
                                               const float* __restrict__ in_w,
                                               const float* __restrict__ in_b,
                                               float* __restrict__ ctx) {
    int bh = blockIdx.x, b = bh >> 4, h = bh & 15;
    int lane = threadIdx.x & 63, l15 = lane & 15, koff = (lane >> 4) * 8;
    int p = l15 & 7;
    size_t uoff = ((size_t)b * 128 + h * 8 + p) * Dn + koff;
    const float* wv = in_w + (size_t)(2 * Dn + h * 64 + l15) * Dn + koff;
    f32x4 acc[4] = {};
    for (int k0 = 0; k0 < Dn; k0 += 32) {
        f32x4 a0 = *(const f32x4*)(Up0 + uoff + k0);
        f32x4 a1 = *(const f32x4*)(Up0 + uoff + k0 + 4);
        f32x4 b0 = *(const f32x4*)(Up1 + uoff + k0);
        f32x4 b1 = *(const f32x4*)(Up1 + uoff + k0 + 4);
        f32x4 d0 = *(const f32x4*)(Up2 + uoff + k0);
        f32x4 d1 = *(const f32x4*)(Up2 + uoff + k0 + 4);
        f32x4 e0 = *(const f32x4*)(Up3 + uoff + k0);
        f32x4 e1 = *(const f32x4*)(Up3 + uoff + k0 + 4);
        short8 av;
#pragma unroll
        for (int i = 0; i < 4; i++) {
            av[i] = f2bf((a0[i] + b0[i]) + (d0[i] + e0[i]));
            av[i + 4] = f2bf((a1[i] + b1[i]) + (d1[i] + e1[i]));
        }
#pragma unroll
        for (int nt = 0; nt < 4; nt++) {
            f32x4 w0 = *(const f32x4*)(wv + (size_t)nt * 16 * Dn + k0);
            f32x4 w1 = *(const f32x4*)(wv + (size_t)nt * 16 * Dn + k0 + 4);
            short8 bv;
#pragma unroll
            for (int i = 0; i < 4; i++) { bv[i] = f2bf(w0[i]); bv[i + 4] = f2bf(w1[i]); }
            acc[nt] = __builtin_amdgcn_mfma_f32_16x16x32_bf16(av, bv, acc[nt], 0, 0, 0);
        }
    }
    if (lane < 32) {                          // rows 0-7 valid (p)
        int prow = (lane >> 4) * 4;
#pragma unroll
        for (int nt = 0; nt < 4; nt++) {
            int d = h * 64 + nt * 16 + l15;
            float bias = in_b[2 * Dn + d];
#pragma unroll
            for (int r = 0; r < 4; r++)
                ctx[(size_t)(b * 8 + prow + r) * Dn + d] = acc[nt][r] + bias;
        }
    }
}

// ---------------------------------------------------------------- pooled = ctx @ out_w^T + out_b (MFMA, f32 operands cvt in-reg)
__global__ __launch_bounds__(256) void pooled_mfma(const float* __restrict__ A,
                                                   const float* __restrict__ B,
                                                   const float* __restrict__ bias,
                                                   float* __restrict__ C, int M) {
    int wave = threadIdx.x >> 6, lane = threadIdx.x & 63;
    int l15 = lane & 15, koff = (lane >> 4) * 8;
    int m0 = blockIdx.x * 64 + (wave >> 1) * 32;
    int n0 = blockIdx.y * 64 + (wave & 1) * 32;
    f32x4 acc[2][2] = {};
    int ra0 = min(m0 + l15, M - 1);
    int ra1 = min(m0 + 16 + l15, M - 1);
    const float* a0p = A + (size_t)ra0 * Dn + koff;
    const float* a1p = A + (size_t)ra1 * Dn + koff;
    const float* b0p = B + (size_t)(n0 + l15) * Dn + koff;
    const float* b1p = B + (size_t)(n0 + 16 + l15) * Dn + koff;
    for (int k0 = 0; k0 < Dn; k0 += 32) {
        short8 av0, av1, bv0, bv1;
        f32x4 x, y;
        x = *(const f32x4*)(a0p + k0); y = *(const f32x4*)(a0p + k0 + 4);
#pragma unroll
        for (int i = 0; i < 4; i++) { av0[i] = f2bf(x[i]); av0[i + 4] = f2bf(y[i]); }
        x = *(const f32x4*)(a1p + k0); y = *(const f32x4*)(a1p + k0 + 4);
#pragma unroll
        for (int i = 0; i < 4; i++) { av1[i] = f2bf(x[i]); av1[i + 4] = f2bf(y[i]); }
        x = *(const f32x4*)(b0p + k0); y = *(const f32x4*)(b0p + k0 + 4);
#pragma unroll
        for (int i = 0; i < 4; i++) { bv0[i] = f2bf(x[i]); bv0[i + 4] = f2bf(y[i]); }
        x = *(const f32x4*)(b1p + k0); y = *(const f32x4*)(b1p + k0 + 4);
#pragma unroll
        for (int i = 0; i < 4; i++) { bv1[i] = f2bf(x[i]); bv1[i + 4] = f2bf(y[i]); }
        acc[0][0] = __builtin_amdgcn_mfma_f32_16x16x32_bf16(av0, bv0, acc[0][0], 0, 0, 0);
        acc[0][1] = __builtin_amdgcn_mfma_f32_16x16x32_bf16(av0, bv1, acc[0][1], 0, 0, 0);
        acc[1][0] = __builtin_amdgcn_mfma_f32_16x16x32_bf16(av1, bv0, acc[1][0], 0, 0, 0);
        acc[1][1] = __builtin_amdgcn_mfma_f32_16x16x32_bf16(av1, bv1, acc[1][1], 0, 0, 0);
    }
#pragma unroll
    for (int mf = 0; mf < 2; mf++) {
        int row0 = m0 + mf * 16 + (lane >> 4) * 4;
#pragma unroll
        for (int nf = 0; nf < 2; nf++) {
            int col = n0 + nf * 16 + l15;
            float bval = bias[col];
#pragma unroll
            for (int r = 0; r < 4; r++) {
                int row = row0 + r;
                if (row < M) C[(size_t)row * Dn + col] = acc[mf][nf][r] + bval;
            }
        }
    }
}

// ---------------------------------------------------------------- bf16 MFMA GEMM: C[M,1024] = A_bf[M,1024] @ B_bf[1024,1024]^T + bias
__global__ __launch_bounds__(256) void wgemm_mfma(const short* __restrict__ Abf,
                                                  const short* __restrict__ Bbf,
                                                  const float* __restrict__ bias,
                                                  float* __restrict__ C, int M) {
    int wave = threadIdx.x >> 6, lane = threadIdx.x & 63;
    int m0 = blockIdx.x * 64 + (wave >> 1) * 32;
    int n0 = blockIdx.y * 64 + (wave & 1) * 32;
    int koff = (lane >> 4) * 8;
    f32x4 acc[2][2] = {};
    int ra0 = min(m0 + (lane & 15), M - 1);
    int ra1 = min(m0 + 16 + (lane & 15), M - 1);
    const short* a0p = Abf + (size_t)ra0 * Dn + koff;
    const short* a1p = Abf + (size_t)ra1 * Dn + koff;
    const short* b0p = Bbf + (size_t)(n0 + (lane & 15)) * Dn + koff;
    const short* b1p = Bbf + (size_t)(n0 + 16 + (lane & 15)) * Dn + koff;
    for (int k0 = 0; k0 < Dn; k0 += 32) {
        short8 av0 = *(const short8*)(a0p + k0);
        short8 av1 = *(const short8*)(a1p + k0);
        short8 bv0 = *(const short8*)(b0p + k0);
        short8 bv1 = *(const short8*)(b1p + k0);
        acc[0][0] = __builtin_amdgcn_mfma_f32_16x16x32_bf16(av0, bv0, acc[0][0], 0, 0, 0);
        acc[0][1] = __builtin_amdgcn_mfma_f32_16x16x32_bf16(av0, bv1, acc[0][1], 0, 0, 0);
        acc[1][0] = __builtin_amdgcn_mfma_f32_16x16x32_bf16(av1, bv0, acc[1][0], 0, 0, 0);
        acc[1][1] = __builtin_amdgcn_mfma_f32_16x16x32_bf16(av1, bv1, acc[1][1], 0, 0, 0);
    }
#pragma unroll
    for (int mf = 0; mf < 2; mf++) {
        int row0 = m0 + mf * 16 + (lane >> 4) * 4;
#pragma unroll
        for (int nf = 0; nf < 2; nf++) {
            int col = n0 + nf * 16 + (lane & 15);
            float bval = bias[col];
#pragma unroll
            for (int r = 0; r < 4; r++) {
                int row = row0 + r;
                if (row < M) C[(size_t)row * Dn + col] = acc[mf][nf][r] + bval;
            }
        }
    }
}

// ---------------------------------------------------------------- block sum helper
__device__ __forceinline__ float block_sum(float v, float* red) {
    int tid = threadIdx.x;
    red[tid] = v;
    __syncthreads();
    for (int off = 128; off > 0; off >>= 1) {
        if (tid < off) red[tid] += red[tid + off];
        __syncthreads();
    }
    float r = red[0];
    __syncthreads();
    return r;
}

// ---------------------------------------------------------------- build summary row + LN_pma + LN_v / LN_g (bf16 out)
__global__ void summary_ln_kernel(const float* __restrict__ hidden,
                                  const float* __restrict__ queries,
                                  const float* __restrict__ pooled,
                                  const int* __restrict__ rsrc,
                                  const float* __restrict__ gpma, const float* __restrict__ bpma,
                                  const float* __restrict__ gv, const float* __restrict__ bv,
                                  const float* __restrict__ gg, const float* __restrict__ bg,
                                  short* __restrict__ lnv, short* __restrict__ lng) {
    __shared__ float red[256];
    int b = blockIdx.x, t = blockIdx.y, tid = threadIdx.x;
    float x[4];
    if (t == 0) {
#pragma unroll
        for (int i = 0; i < 4; i++)
            x[i] = hidden[(size_t)b * Sn * Dn + tid + i * 256];
    } else if (t < 1 + Pn) {
        int p = t - 1;
#pragma unroll
        for (int i = 0; i < 4; i++) {
            int c = tid + i * 256;
            x[i] = queries[p * Dn + c] + pooled[((size_t)b * Pn + p) * Dn + c];
        }
    } else {
        int src = rsrc[b * RECn + (t - 9)];
        if (src >= 0) {
#pragma unroll
            for (int i = 0; i < 4; i++)
                x[i] = hidden[((size_t)b * Sn + src) * Dn + tid + i * 256];
        } else {
#pragma unroll
            for (int i = 0; i < 4; i++) x[i] = 0.0f;
        }
    }
    if (t >= 1 && t < 1 + Pn) {
        float mu = block_sum(x[0] + x[1] + x[2] + x[3], red) * (1.0f / Dn);
        float d2 = 0.0f;
#pragma unroll
        for (int i = 0; i < 4; i++) { float d = x[i] - mu; d2 += d * d; }
        float inv = rsqrtf(block_sum(d2, red) * (1.0f / Dn) + 1e-5f);
#pragma unroll
        for (int i = 0; i < 4; i++) {
            int c = tid + i * 256;
            x[i] = (x[i] - mu) * inv * gpma[c] + bpma[c];
        }
    }
    float mu = block_sum(x[0] + x[1] + x[2] + x[3], red) * (1.0f / Dn);
    float d2 = 0.0f;
#pragma unroll
    for (int i = 0; i < 4; i++) { float d = x[i] - mu; d2 += d * d; }
    float inv = rsqrtf(block_sum(d2, red) * (1.0f / Dn) + 1e-5f);
    size_t row = (size_t)(b * Tn + t) * Dn;
#pragma unroll
    for (int i = 0; i < 4; i++) {
        int c = tid + i * 256;
        float xh = (x[i] - mu) * inv;
        lnv[row + c] = f2bf(xh * gv[c] + bv[c]);
        lng[row + c] = f2bf(xh * gg[c] + bg[c]);
    }
}

// ---------------------------------------------------------------- gated = sigmoid(c2) * silu(c1) * mask
__global__ void gated_kernel(const float* __restrict__ c1, const float* __restrict__ c2,
                             const float* __restrict__ maskf, float* __restrict__ out) {
    int gi = blockIdx.x * blockDim.x + threadIdx.x;
    int row = gi >> 10;
    float m = maskf[row];
    float a = c1[gi], g = c2[gi];
    float sv = a / (1.0f + expf(-a));
    float sg = 1.0f / (1.0f + expf(-g));
    out[gi] = sg * sv * m;
}

// ================================================================ launch
extern "C" void kernel_launch(void* const* d_in, const int* in_sizes, int n_in,
                              void* d_out, int out_size, void* d_ws, size_t ws_size,
                              hipStream_t stream) {
    const float* hidden = (const float*)d_in[0];
    const void* valid_raw = d_in[1];
    const float* queries = (const float*)d_in[2];
    const float* in_w = (const float*)d_in[3];
    const float* in_b = (const float*)d_in[4];
    const float* out_w = (const float*)d_in[5];
    const float* out_b = (const float*)d_in[6];
    const float* ln_pma_g = (const float*)d_in[7];
    const float* ln_pma_b = (const float*)d_in[8];
    const float* ln_v_g = (const float*)d_in[9];
    const float* ln_v_b = (const float*)d_in[10];
    const float* W_v = (const float*)d_in[11];
    const float* b_v = (const float*)d_in[12];
    const float* ln_g_g = (const float*)d_in[13];
    const float* ln_g_b = (const float*)d_in[14];
    const float* W_g = (const float*)d_in[15];
    const float* b_g = (const float*)d_in[16];

    float* ws = (float*)d_ws;
    float* out = (float*)d_out;

    // workspace layout (float offsets):
    float* SC      = ws;                         // scores f32: 4,194,304 f (dead after softmax)
    short* attn_bf = (short*)(ws + 4194304);     // 4,194,304 shorts = 2,097,152 f
    float* Up0     = ws;                         // overlay dead SC region
    float* Up1     = ws + 2097152;               // overlay dead SC region
    float* Up2     = ws + 6291456;               // 2,097,152 f
    float* Up3     = ws + 8388608;               // 2,097,152 f (ends 10,485,760)
    float* qbuf    = ws + 10485760;              // 8,192
    short* Amat_bf = (short*)(ws + 10493952);    // 65,536 f
    float* c0      = ws + 10559488;              // 256
    float* ctx     = ws + 10559744;              // 131,072
    float* pooled  = ws + 10690816;              // 131,072
    short* Wv_bf   = (short*)(ws + 10821888);    // 524,288 f
    short* Wg_bf   = (short*)(ws + 11346176);    // 524,288 f
    int*   ivals   = (int*)(ws + 11870464);
    int* totals = ivals;                         // 16
    int* rsrc = ivals + 16;                      // 1024
    int* flag = ivals + 16 + 1024;               // 16
    unsigned char* canon = (unsigned char*)(ivals + 16 + 1024 + 16); // 32768 B
    // post-ctx overlays (Up0..3 dead after ctx):
    short* lnv_bf = (short*)ws;
    short* lng_bf = (short*)(ws + 622592);
    float* c1 = ws + 1245184;
    float* c2 = ws + 2441216;                    // ends 3,637,248 OK
    float* maskf = out + (size_t)Bn * Tn * Dn;

    const int M2 = Bn * Tn; // 1168

    detect_mask_kernel<<<1, 256, 0, stream>>>((const unsigned char*)valid_raw, flag);
    canon_mask_kernel<<<(Bn * Sn) / 256, 256, 0, stream>>>(valid_raw, flag, canon);
    prep_kernel<<<Bn, 256, 0, stream>>>(canon, totals, rsrc, maskf);
    q_kernel<<<(Pn * Dn) / 4, 256, 0, stream>>>(queries, in_w, in_b, qbuf);
    A_kernel<<<dim3(Hn, 4), 256, 0, stream>>>(qbuf, in_w, in_b, Amat_bf, c0);
    wcvt_kernel<<<512, 256, 0, stream>>>(W_v, Wv_bf, Dn * Dn);
    wcvt_kernel<<<512, 256, 0, stream>>>(W_g, Wg_bf, Dn * Dn);
    scores_mfma<<<(Bn * Sn) / 64, 256, 0, stream>>>(hidden, Amat_bf, c0, canon, SC);
    softmax_kernel<<<Bn * 128, 256, 0, stream>>>(SC, attn_bf);
    U_mfma<<<dim3(16, Bn, 4), 512, 0, stream>>>(attn_bf, hidden, Up0, Up1, Up2, Up3);
    ctx_mfma<<<Bn * Hn, 64, 0, stream>>>(Up0, Up1, Up2, Up3, in_w, in_b, ctx);
    pooled_mfma<<<dim3(2, 16), 256, 0, stream>>>(ctx, out_w, out_b, pooled, Bn * Pn);
    summary_ln_kernel<<<dim3(Bn, Tn), 256, 0, stream>>>(hidden, queries, pooled, rsrc,
                                                        ln_pma_g, ln_pma_b, ln_v_g, ln_v_b,
                                                        ln_g_g, ln_g_b, lnv_bf, lng_bf);
    wgemm_mfma<<<dim3((M2 + 63) / 64, 16), 256, 0, stream>>>(lnv_bf, Wv_bf, b_v, c1, M2);
    wgemm_mfma<<<dim3((M2 + 63) / 64, 16), 256, 0, stream>>>(lng_bf, Wg_bf, b_g, c2, M2);
    gated_kernel<<<(Bn * Tn * Dn) / 256, 256, 0, stream>>>(c1, c2, maskf, out);
}

// Round 11
// 234.616 us; speedup vs baseline: 1.0829x; 1.0626x over previous
//
#include <hip/hip_runtime.h>
#include <hip/hip_bf16.h>
#include <math.h>

// Dims fixed by setup_inputs(): B=16, S=2048, D=1024, H=16, hd=64, P=8,
// cls=1, pma=8, recent=64, T=73.

#define Bn 16
#define Sn 2048
#define Dn 1024
#define Hn 16
#define Pn 8
#define Tn 73
#define RECn 64

typedef __attribute__((ext_vector_type(8))) short short8;
typedef __attribute__((ext_vector_type(4))) float f32x4;

__device__ __forceinline__ short f2bf(float x) {
    union { __hip_bfloat16 h; short s; } u;
    u.h = __float2bfloat16(x);   // native v_cvt, RNE
    return u.s;
}
__device__ __forceinline__ float bf2f(short s) {
    return __uint_as_float(((unsigned)(unsigned short)s) << 16);
}

// valid_mask accessor: dtype decided at runtime by flag (1 = uint8, 0 = int32).
__device__ __forceinline__ bool mask_at(const void* raw, int f, size_t idx) {
    return f ? (((const unsigned char*)raw)[idx] != 0)
             : (((const int*)raw)[idx] != 0);
}

// async global->LDS DMA, 16B per lane. LDS dest = wave-uniform base + lane*16.
__device__ __forceinline__ void gload_lds16(const void* g, void* l) {
    __builtin_amdgcn_global_load_lds((const __attribute__((address_space(1))) void*)g,
                                     (__attribute__((address_space(3))) void*)l, 16, 0, 0);
}

// XOR swizzle helper for U staging.
__device__ __forceinline__ int swzP(int row, int ks, int pitch) {
    return row * pitch + (ks ^ ((row & 7) << 3));
}

// ---------------------------------------------------------------- setup1: mask-dtype detect (block 2048) + q = queries@Wq^T+bq (blocks 0..2047)
__global__ __launch_bounds__(256) void setup1_kernel(const float* __restrict__ queries,
                                                     const float* __restrict__ in_w,
                                                     const float* __restrict__ in_b,
                                                     const unsigned char* __restrict__ raw,
                                                     float* __restrict__ q,
                                                     int* __restrict__ flag) {
    if (blockIdx.x == 2048) {
        __shared__ int any;
        if (threadIdx.x == 0) any = 0;
        __syncthreads();
        const uint4* r4 = (const uint4*)raw;
        int local = 0;
        for (int i = threadIdx.x; i < (Bn * Sn) / 16; i += blockDim.x) {
            uint4 w = r4[i];
            if ((w.x & 0xFFFFFF00u) | (w.y & 0xFFFFFF00u) |
                (w.z & 0xFFFFFF00u) | (w.w & 0xFFFFFF00u)) local = 1;
        }
        if (local) any = 1;                   // benign race
        __syncthreads();
        if (threadIdx.x == 0) *flag = any;
        return;
    }
    int wid = (blockIdx.x * blockDim.x + threadIdx.x) >> 6;
    int lane = threadIdx.x & 63;
    if (wid >= Pn * Dn) return;
    int p = wid >> 10, j = wid & 1023;
    float acc = 0.0f;
    for (int c = lane; c < Dn; c += 64)
        acc += queries[p * Dn + c] * in_w[(size_t)j * Dn + c];
#pragma unroll
    for (int off = 32; off > 0; off >>= 1) acc += __shfl_down(acc, off);
    if (lane == 0) q[wid] = acc + in_b[j];
}

// ---------------------------------------------------------------- setup2: A matrix (blocks 0..63) + prep scan (blocks 64..79)
__global__ __launch_bounds__(256) void setup2_kernel(const float* __restrict__ q,
                                                     const float* __restrict__ in_w,
                                                     const float* __restrict__ in_b,
                                                     const void* __restrict__ raw,
                                                     const int* __restrict__ flag,
                                                     short* __restrict__ Amat_bf,
                                                     float* __restrict__ c0,
                                                     int* __restrict__ totals,
                                                     int* __restrict__ rsrc,
                                                     float* __restrict__ maskf) {
    __shared__ float qs[8][64];
    __shared__ int lc[256];
    if (blockIdx.x < 64) {                    // ---- A_bf[h*8+p,c] + c0
        int h = blockIdx.x >> 2, cblk = blockIdx.x & 3;
        int c = cblk * 256 + threadIdx.x;
        for (int i = threadIdx.x; i < 512; i += 256) {
            int p = i >> 6, d = i & 63;
            qs[p][d] = q[p * Dn + h * 64 + d];
        }
        __syncthreads();
        float acc[8] = {};
#pragma unroll 8
        for (int d = 0; d < 64; d++) {
            float w = in_w[(size_t)(Dn + h * 64 + d) * Dn + c];
#pragma unroll
            for (int p = 0; p < 8; p++) acc[p] = fmaf(qs[p][d], w, acc[p]);
        }
#pragma unroll
        for (int p = 0; p < 8; p++)
            Amat_bf[(size_t)(h * 8 + p) * Dn + c] = f2bf(acc[p] * 0.125f);
        if (cblk == 0 && threadIdx.x < 8) {
            int p = threadIdx.x;
            float a = 0.0f;
            for (int d = 0; d < 64; d++) a += qs[p][d] * in_b[Dn + h * 64 + d];
            c0[h * 8 + p] = a * 0.125f;
        }
        return;
    }
    // ---- prep: per-batch scan, recent gather indices, summary mask
    int b = blockIdx.x - 64, t = threadIdx.x;
    int f = *flag;
    const int SP = Sn - 1;                    // 2047
    if (t < RECn) rsrc[b * RECn + t] = -1;
    int base = t * 8;
    unsigned char m[8];
    int cnt = 0;
#pragma unroll
    for (int i = 0; i < 8; i++) {
        int idx = base + i;
        m[i] = (idx < SP) ? (mask_at(raw, f, (size_t)b * Sn + 1 + idx) ? 1 : 0) : 0;
        cnt += m[i];
    }
    lc[t] = cnt;
    __syncthreads();
    for (int off = 1; off < 256; off <<= 1) {
        int add = (t >= off) ? lc[t - off] : 0;
        __syncthreads();
        lc[t] += add;
        __syncthreads();
    }
    int total = lc[255];
    int run = lc[t] - cnt;                    // exclusive prefix
#pragma unroll
    for (int i = 0; i < 8; i++) {
        if (m[i]) {
            run++;
            int rank = total - run;
            if (rank < RECn) rsrc[b * RECn + (RECn - 1 - rank)] = base + i + 1;
        }
    }
    if (t == 0) totals[b] = total;
    if (t < Tn) {
        float mv;
        if (t == 0) mv = mask_at(raw, f, (size_t)b * Sn) ? 1.0f : 0.0f;
        else if (t < 1 + Pn) mv = 1.0f;
        else mv = ((t - 9) >= RECn - total) ? 1.0f : 0.0f;
        maskf[b * Tn + t] = mv;
    }
}

// ---------------------------------------------------------------- scores[b,hp,s] = hidden[b,s,:]@A[hp,:] + c0 (MFMA bf16), masked
// m97-replica: 512 blocks x 256 thr (4 waves). Tile 64 s x 128 hp, BK=32.
// global_load_lds(16B) double-buffered staging, one barrier per K-step,
// source-address swizzle -> 2-way (free) bank access on ds_reads.
__global__ __launch_bounds__(256) void scores_mfma(const float* __restrict__ hidden,
                                                   const short* __restrict__ Amat_bf,
                                                   const float* __restrict__ c0,
                                                   const void* __restrict__ raw,
                                                   const int* __restrict__ flag,
                                                   float* __restrict__ scores) {
    __shared__ float Af[2][64 * 32];          // A: slot16B = s*8 + (j ^ (s&7))
    __shared__ short Bs[2][128 * 32];         // B: slot16B = hp*4 + (q ^ ((hp>>1)&3))
    int tid = threadIdx.x, wave = tid >> 6, lane = tid & 63;
    int l15 = lane & 15, q = lane >> 4;
    int m0 = blockIdx.x * 64;
    int b = m0 >> 11, s_base = m0 & 2047;
    int ws = wave >> 1, wh = wave & 1;
    int s0 = ws * 32, hp0 = wh * 64;

    auto stage = [&](int bb, int k0) {
#pragma unroll
        for (int u = 0; u < 2; u++) {         // A: 512 slots of 16B
            int i = tid + u * 256;
            int s = i >> 3, j = (i & 7) ^ (s & 7);
            gload_lds16(hidden + (size_t)(m0 + s) * Dn + k0 + j * 4, &Af[bb][i * 4]);
        }
#pragma unroll
        for (int u = 0; u < 2; u++) {         // B: 512 slots of 16B
            int i = tid + u * 256;
            int hp = i >> 2, qq = (i & 3) ^ ((hp >> 1) & 3);
            gload_lds16(Amat_bf + (size_t)hp * Dn + k0 + qq * 8, &Bs[bb][i * 8]);
        }
    };

    f32x4 acc[2][4] = {};
    stage(0, 0);
    __syncthreads();

    for (int t = 0; t < 32; t++) {
        int bb = t & 1;
        if (t + 1 < 32) stage(bb ^ 1, (t + 1) * 32);
        short8 av[2], bv[4];
#pragma unroll
        for (int f = 0; f < 2; f++) {
            int s = s0 + f * 16 + l15;
            int base = s * 8;
            f32x4 lo = *(const f32x4*)&Af[bb][(base + ((2 * q) ^ (s & 7))) * 4];
            f32x4 hi = *(const f32x4*)&Af[bb][(base + ((2 * q + 1) ^ (s & 7))) * 4];
#pragma unroll
            for (int i = 0; i < 4; i++) { av[f][i] = f2bf(lo[i]); av[f][i + 4] = f2bf(hi[i]); }
        }
#pragma unroll
        for (int f = 0; f < 4; f++) {
            int hp = hp0 + f * 16 + l15;
            bv[f] = *(const short8*)&Bs[bb][(hp * 4 + (q ^ ((hp >> 1) & 3))) * 8];
        }
#pragma unroll
        for (int fa = 0; fa < 2; fa++)
#pragma unroll
            for (int fb = 0; fb < 4; fb++)
                acc[fa][fb] = __builtin_amdgcn_mfma_f32_16x16x32_bf16(av[fa], bv[fb], acc[fa][fb], 0, 0, 0);
        __syncthreads();
    }

    int fl = *flag;
#pragma unroll
    for (int fa = 0; fa < 2; fa++) {
        int srow = s_base + s0 + fa * 16 + q * 4;
        size_t vbase = (size_t)b * Sn + srow;
        bool ok0 = mask_at(raw, fl, vbase), ok1 = mask_at(raw, fl, vbase + 1);
        bool ok2 = mask_at(raw, fl, vbase + 2), ok3 = mask_at(raw, fl, vbase + 3);
#pragma unroll
        for (int fb = 0; fb < 4; fb++) {
            int hp = hp0 + fb * 16 + l15;
            float cc = c0[hp];
            f32x4 st;
            st[0] = ok0 ? acc[fa][fb][0] + cc : -1.0e9f;
            st[1] = ok1 ? acc[fa][fb][1] + cc : -1.0e9f;
            st[2] = ok2 ? acc[fa][fb][2] + cc : -1.0e9f;
            st[3] = ok3 ? acc[fa][fb][3] + cc : -1.0e9f;
            *(f32x4*)(scores + (size_t)(b * 128 + hp) * Sn + srow) = st;
        }
    }
}

// ---------------------------------------------------------------- softmax over s; writes bf16 attn
__global__ __launch_bounds__(256) void softmax_kernel(const float* __restrict__ scores,
                                                      short* __restrict__ attn_bf) {
    const float* row = scores + (size_t)blockIdx.x * Sn;
    short* orow = attn_bf + (size_t)blockIdx.x * Sn;
    int t = threadIdx.x;
    __shared__ float red[256];
    f32x4 v0 = *(const f32x4*)(row + t * 8);
    f32x4 v1 = *(const f32x4*)(row + t * 8 + 4);
    float mx = -1.0e30f;
#pragma unroll
    for (int i = 0; i < 4; i++) { mx = fmaxf(mx, v0[i]); mx = fmaxf(mx, v1[i]); }
    red[t] = mx;
    __syncthreads();
    for (int off = 128; off > 0; off >>= 1) {
        if (t < off) red[t] = fmaxf(red[t], red[t + off]);
        __syncthreads();
    }
    mx = red[0];
    __syncthreads();
    float e[8];
    float sum = 0.0f;
#pragma unroll
    for (int i = 0; i < 4; i++) {
        e[i] = expf(v0[i] - mx); sum += e[i];
        e[i + 4] = expf(v1[i] - mx); sum += e[i + 4];
    }
    red[t] = sum;
    __syncthreads();
    for (int off = 128; off > 0; off >>= 1) {
        if (t < off) red[t] += red[t + off];
        __syncthreads();
    }
    float inv = 1.0f / red[0];
    short8 o;
#pragma unroll
    for (int i = 0; i < 8; i++) o[i] = f2bf(e[i] * inv);
    *(short8*)(orow + t * 8) = o;
}

// ---------------------------------------------------------------- U partials (bf16): Up[b,hp,c] = sum_{s in z-chunk} attn*hidden
// grid (16 c-tiles of 64, 16 b, 4 z) x 512 threads. Hidden z-chunk staged
// transposed ONCE (64KB LDS, 2 blocks/CU); attn streams 4-deep; barrier-free.
__global__ __launch_bounds__(512) void U_mfma(const short* __restrict__ attn_bf,
                                              const float* __restrict__ hidden,
                                              short* __restrict__ Up0,
                                              short* __restrict__ Up1,
                                              short* __restrict__ Up2,
                                              short* __restrict__ Up3) {
    __shared__ short Hs[64 * 512];            // 64 c x 512 s, swizzled
    int n0 = blockIdx.x * 64, b = blockIdx.y, z = blockIdx.z;
    int zbase = z * 512;
    short* Up = (z == 0) ? Up0 : (z == 1) ? Up1 : (z == 2) ? Up2 : Up3;
    int tid = threadIdx.x, wave = tid >> 6, lane = tid & 63;
    int l15 = lane & 15, q = lane >> 4;

    {   // stage: thread t owns s-row = tid; transpose-write 64 c values
        const float* src = hidden + ((size_t)b * Sn + zbase + tid) * Dn + n0;
#pragma unroll
        for (int c8 = 0; c8 < 64; c8 += 8) {
            f32x4 x = *(const f32x4*)(src + c8);
            f32x4 y = *(const f32x4*)(src + c8 + 4);
#pragma unroll
            for (int i = 0; i < 4; i++) {
                int c = c8 + i;
                Hs[c * 512 + (tid ^ ((c & 7) << 3))] = f2bf(x[i]);
            }
#pragma unroll
            for (int i = 0; i < 4; i++) {
                int c = c8 + 4 + i;
                Hs[c * 512 + (tid ^ ((c & 7) << 3))] = f2bf(y[i]);
            }
        }
    }
    __syncthreads();                          // the only barrier

    const short* ap = attn_bf + ((size_t)b * 128 + wave * 16 + l15) * Sn + zbase + q * 8;
    f32x4 acc[4] = {};
    short8 pa4[4];
#pragma unroll
    for (int d = 0; d < 4; d++) pa4[d] = *(const short8*)(ap + d * 32);
#pragma unroll
    for (int ic = 0; ic < 16; ic++) {
        short8 av = pa4[ic & 3];
        if (ic + 4 < 16) pa4[ic & 3] = *(const short8*)(ap + (ic + 4) * 32);
#pragma unroll
        for (int nf = 0; nf < 4; nf++) {
            short8 bv = *(const short8*)(&Hs[swzP(nf * 16 + l15, ic * 32 + q * 8, 512)]);
            acc[nf] = __builtin_amdgcn_mfma_f32_16x16x32_bf16(av, bv, acc[nf], 0, 0, 0);
        }
    }
    int hp = wave * 16 + q * 4;
#pragma unroll
    for (int nf = 0; nf < 4; nf++) {
        int c = n0 + nf * 16 + l15;
        short* up = Up + (size_t)(b * 128 + hp) * Dn + c;
#pragma unroll
        for (int r = 0; r < 4; r++) up[(size_t)r * Dn] = f2bf(acc[nf][r]);
    }
}

// ---------------------------------------------------------------- ctx[bp, h*64+d] = (sum Up)[b,h*8+p,:] . Wv[h*64+d,:] + bv  (MFMA)
__global__ __launch_bounds__(64) void ctx_mfma(const short* __restrict__ Up0,
                                               const short* __restrict__ Up1,
                                               const short* __restrict__ Up2,
                                               const short* __restrict__ Up3,
                                               const float* __restrict__ in_w,
                                               const float* __restrict__ in_b,
                                               float* __restrict__ ctx) {
    int bh = blockIdx.x, b = bh >> 4, h = bh & 15;
    int lane = threadIdx.x & 63, l15 = lane & 15, koff = (lane >> 4) * 8;
    int p = l15 & 7;
    size_t uoff = ((size_t)b * 128 + h * 8 + p) * Dn + koff;
    const float* wv = in_w + (size_t)(2 * Dn + h * 64 + l15) * Dn + koff;
    f32x4 acc[4] = {};
    for (int k0 = 0; k0 < Dn; k0 += 32) {
        short8 s0 = *(const short8*)(Up0 + uoff + k0);
        short8 s1 = *(const short8*)(Up1 + uoff + k0);
        short8 s2 = *(const short8*)(Up2 + uoff + k0);
        short8 s3 = *(const short8*)(Up3 + uoff + k0);
        short8 av;
#pragma unroll
        for (int i = 0; i < 8; i++)
            av[i] = f2bf((bf2f(s0[i]) + bf2f(s1[i])) + (bf2f(s2[i]) + bf2f(s3[i])));
#pragma unroll
        for (int nt = 0; nt < 4; nt++) {
            f32x4 w0 = *(const f32x4*)(wv + (size_t)nt * 16 * Dn + k0);
            f32x4 w1 = *(const f32x4*)(wv + (size_t)nt * 16 * Dn + k0 + 4);
            short8 bv;
#pragma unroll
            for (int i = 0; i < 4; i++) { bv[i] = f2bf(w0[i]); bv[i + 4] = f2bf(w1[i]); }
            acc[nt] = __builtin_amdgcn_mfma_f32_16x16x32_bf16(av, bv, acc[nt], 0, 0, 0);
        }
    }
    if (lane < 32) {                          // rows 0-7 valid (p)
        int prow = (lane >> 4) * 4;
#pragma unroll
        for (int nt = 0; nt < 4; nt++) {
            int d = h * 64 + nt * 16 + l15;
            float bias = in_b[2 * Dn + d];
#pragma unroll
            for (int r = 0; r < 4; r++)
                ctx[(size_t)(b * 8 + prow + r) * Dn + d] = acc[nt][r] + bias;
        }
    }
}

// ---------------------------------------------------------------- pooled = ctx @ out_w^T + out_b (MFMA, f32 operands cvt in-reg)
__global__ __launch_bounds__(256) void pooled_mfma(const float* __restrict__ A,
                                                   const float* __restrict__ B,
                                                   const float* __restrict__ bias,
                                                   float* __restrict__ C, int M) {
    int wave = threadIdx.x >> 6, lane = threadIdx.x & 63;
    int l15 = lane & 15, koff = (lane >> 4) * 8;
    int m0 = blockIdx.x * 64 + (wave >> 1) * 32;
    int n0 = blockIdx.y * 64 + (wave & 1) * 32;
    f32x4 acc[2][2] = {};
    int ra0 = min(m0 + l15, M - 1);
    int ra1 = min(m0 + 16 + l15, M - 1);
    const float* a0p = A + (size_t)ra0 * Dn + koff;
    const float* a1p = A + (size_t)ra1 * Dn + koff;
    const float* b0p = B + (size_t)(n0 + l15) * Dn + koff;
    const float* b1p = B + (size_t)(n0 + 16 + l15) * Dn + koff;
    for (int k0 = 0; k0 < Dn; k0 += 32) {
        short8 av0, av1, bv0, bv1;
        f32x4 x, y;
        x = *(const f32x4*)(a0p + k0); y = *(const f32x4*)(a0p + k0 + 4);
#pragma unroll
        for (int i = 0; i < 4; i++) { av0[i] = f2bf(x[i]); av0[i + 4] = f2bf(y[i]); }
        x = *(const f32x4*)(a1p + k0); y = *(const f32x4*)(a1p + k0 + 4);
#pragma unroll
        for (int i = 0; i < 4; i++) { av1[i] = f2bf(x[i]); av1[i + 4] = f2bf(y[i]); }
        x = *(const f32x4*)(b0p + k0); y = *(const f32x4*)(b0p + k0 + 4);
#pragma unroll
        for (int i = 0; i < 4; i++) { bv0[i] = f2bf(x[i]); bv0[i + 4] = f2bf(y[i]); }
        x = *(const f32x4*)(b1p + k0); y = *(const f32x4*)(b1p + k0 + 4);
#pragma unroll
        for (int i = 0; i < 4; i++) { bv1[i] = f2bf(x[i]); bv1[i + 4] = f2bf(y[i]); }
        acc[0][0] = __builtin_amdgcn_mfma_f32_16x16x32_bf16(av0, bv0, acc[0][0], 0, 0, 0);
        acc[0][1] = __builtin_amdgcn_mfma_f32_16x16x32_bf16(av0, bv1, acc[0][1], 0, 0, 0);
        acc[1][0] = __builtin_amdgcn_mfma_f32_16x16x32_bf16(av1, bv0, acc[1][0], 0, 0, 0);
        acc[1][1] = __builtin_amdgcn_mfma_f32_16x16x32_bf16(av1, bv1, acc[1][1], 0, 0, 0);
    }
#pragma unroll
    for (int mf = 0; mf < 2; mf++) {
        int row0 = m0 + mf * 16 + (lane >> 4) * 4;
#pragma unroll
        for (int nf = 0; nf < 2; nf++) {
            int col = n0 + nf * 16 + l15;
            float bval = bias[col];
#pragma unroll
            for (int r = 0; r < 4; r++) {
                int row = row0 + r;
                if (row < M) C[(size_t)row * Dn + col] = acc[mf][nf][r] + bval;
            }
        }
    }
}

// ---------------------------------------------------------------- merged W-GEMMs: z=0: c1=lnv@Wv^T+bv, z=1: c2=lng@Wg^T+bg
// A bf16, B f32 with in-reg cvt (weights stay f32; L2-resident re-reads).
__global__ __launch_bounds__(256) void wgemm_mfma(const short* __restrict__ lnv,
                                                  const short* __restrict__ lng,
                                                  const float* __restrict__ Wv,
                                                  const float* __restrict__ Wg,
                                                  const float* __restrict__ bv_,
                                                  const float* __restrict__ bg_,
                                                  float* __restrict__ c1,
                                                  float* __restrict__ c2, int M) {
    int z = blockIdx.z;
    const short* Abf = z ? lng : lnv;
    const float* Bw = z ? Wg : Wv;
    const float* bias = z ? bg_ : bv_;
    float* C = z ? c2 : c1;
    int wave = threadIdx.x >> 6, lane = threadIdx.x & 63;
    int l15 = lane & 15, koff = (lane >> 4) * 8;
    int m0 = blockIdx.x * 64 + (wave >> 1) * 32;
    int n0 = blockIdx.y * 64 + (wave & 1) * 32;
    f32x4 acc[2][2] = {};
    int ra0 = min(m0 + l15, M - 1);
    int ra1 = min(m0 + 16 + l15, M - 1);
    const short* a0p = Abf + (size_t)ra0 * Dn + koff;
    const short* a1p = Abf + (size_t)ra1 * Dn + koff;
    const float* b0p = Bw + (size_t)(n0 + l15) * Dn + koff;
    const float* b1p = Bw + (size_t)(n0 + 16 + l15) * Dn + koff;
    for (int k0 = 0; k0 < Dn; k0 += 32) {
        short8 av0 = *(const short8*)(a0p + k0);
        short8 av1 = *(const short8*)(a1p + k0);
        short8 bv0, bv1;
        f32x4 x, y;
        x = *(const f32x4*)(b0p + k0); y = *(const f32x4*)(b0p + k0 + 4);
#pragma unroll
        for (int i = 0; i < 4; i++) { bv0[i] = f2bf(x[i]); bv0[i + 4] = f2bf(y[i]); }
        x = *(const f32x4*)(b1p + k0); y = *(const f32x4*)(b1p + k0 + 4);
#pragma unroll
        for (int i = 0; i < 4; i++) { bv1[i] = f2bf(x[i]); bv1[i + 4] = f2bf(y[i]); }
        acc[0][0] = __builtin_amdgcn_mfma_f32_16x16x32_bf16(av0, bv0, acc[0][0], 0, 0, 0);
        acc[0][1] = __builtin_amdgcn_mfma_f32_16x16x32_bf16(av0, bv1, acc[0][1], 0, 0, 0);
        acc[1][0] = __builtin_amdgcn_mfma_f32_16x16x32_bf16(av1, bv0, acc[1][0], 0, 0, 0);
        acc[1][1] = __builtin_amdgcn_mfma_f32_16x16x32_bf16(av1, bv1, acc[1][1], 0, 0, 0);
    }
#pragma unroll
    for (int mf = 0; mf < 2; mf++) {
        int row0 = m0 + mf * 16 + (lane >> 4) * 4;
#pragma unroll
        for (int nf = 0; nf < 2; nf++) {
            int col = n0 + nf * 16 + l15;
            float bval = bias[col];
#pragma unroll
            for (int r = 0; r < 4; r++) {
                int row = row0 + r;
                if (row < M) C[(size_t)row * Dn + col] = acc[mf][nf][r] + bval;
            }
        }
    }
}

// ---------------------------------------------------------------- block sum helper
__device__ __forceinline__ float block_sum(float v, float* red) {
    int tid = threadIdx.x;
    red[tid] = v;
    __syncthreads();
    for (int off = 128; off > 0; off >>= 1) {
        if (tid < off) red[tid] += red[tid + off];
        __syncthreads();
    }
    float r = red[0];
    __syncthreads();
    return r;
}

// ---------------------------------------------------------------- build summary row + LN_pma + LN_v / LN_g (bf16 out)
__global__ void summary_ln_kernel(const float* __restrict__ hidden,
                                  const float* __restrict__ queries,
                                  const float* __restrict__ pooled,
                                  const int* __restrict__ rsrc,
                                  const float* __restrict__ gpma, const float* __restrict__ bpma,
                                  const float* __restrict__ gv, const float* __restrict__ bv,
                                  const float* __restrict__ gg, const float* __restrict__ bg,
                                  short* __restrict__ lnv, short* __restrict__ lng) {
    __shared__ float red[256];
    int b = blockIdx.x, t = blockIdx.y, tid = threadIdx.x;
    float x[4];
    if (t == 0) {
#pragma unroll
        for (int i = 0; i < 4; i++)
            x[i] = hidden[(size_t)b * Sn * Dn + tid + i * 256];
    } else if (t < 1 + Pn) {
        int p = t - 1;
#pragma unroll
        for (int i = 0; i < 4; i++) {
            int c = tid + i * 256;
            x[i] = queries[p * Dn + c] + pooled[((size_t)b * Pn + p) * Dn + c];
        }
    } else {
        int src = rsrc[b * RECn + (t - 9)];
        if (src >= 0) {
#pragma unroll
            for (int i = 0; i < 4; i++)
                x[i] = hidden[((size_t)b * Sn + src) * Dn + tid + i * 256];
        } else {
#pragma unroll
            for (int i = 0; i < 4; i++) x[i] = 0.0f;
        }
    }
    if (t >= 1 && t < 1 + Pn) {
        float mu = block_sum(x[0] + x[1] + x[2] + x[3], red) * (1.0f / Dn);
        float d2 = 0.0f;
#pragma unroll
        for (int i = 0; i < 4; i++) { float d = x[i] - mu; d2 += d * d; }
        float inv = rsqrtf(block_sum(d2, red) * (1.0f / Dn) + 1e-5f);
#pragma unroll
        for (int i = 0; i < 4; i++) {
            int c = tid + i * 256;
            x[i] = (x[i] - mu) * inv * gpma[c] + bpma[c];
        }
    }
    float mu = block_sum(x[0] + x[1] + x[2] + x[3], red) * (1.0f / Dn);
    float d2 = 0.0f;
#pragma unroll
    for (int i = 0; i < 4; i++) { float d = x[i] - mu; d2 += d * d; }
    float inv = rsqrtf(block_sum(d2, red) * (1.0f / Dn) + 1e-5f);
    size_t row = (size_t)(b * Tn + t) * Dn;
#pragma unroll
    for (int i = 0; i < 4; i++) {
        int c = tid + i * 256;
        float xh = (x[i] - mu) * inv;
        lnv[row + c] = f2bf(xh * gv[c] + bv[c]);
        lng[row + c] = f2bf(xh * gg[c] + bg[c]);
    }
}

// ---------------------------------------------------------------- gated = sigmoid(c2) * silu(c1) * mask
__global__ void gated_kernel(const float* __restrict__ c1, const float* __restrict__ c2,
                             const float* __restrict__ maskf, float* __restrict__ out) {
    int gi = blockIdx.x * blockDim.x + threadIdx.x;
    int row = gi >> 10;
    float m = maskf[row];
    float a = c1[gi], g = c2[gi];
    float sv = a / (1.0f + expf(-a));
    float sg = 1.0f / (1.0f + expf(-g));
    out[gi] = sg * sv * m;
}

// ================================================================ launch
extern "C" void kernel_launch(void* const* d_in, const int* in_sizes, int n_in,
                              void* d_out, int out_size, void* d_ws, size_t ws_size,
                              hipStream_t stream) {
    const float* hidden = (const float*)d_in[0];
    const void* valid_raw = d_in[1];
    const float* queries = (const float*)d_in[2];
    const float* in_w = (const float*)d_in[3];
    const float* in_b = (const float*)d_in[4];
    const float* out_w = (const float*)d_in[5];
    const float* out_b = (const float*)d_in[6];
    const float* ln_pma_g = (const float*)d_in[7];
    const float* ln_pma_b = (const float*)d_in[8];
    const float* ln_v_g = (const float*)d_in[9];
    const float* ln_v_b = (const float*)d_in[10];
    const float* W_v = (const float*)d_in[11];
    const float* b_v = (const float*)d_in[12];
    const float* ln_g_g = (const float*)d_in[13];
    const float* ln_g_b = (const float*)d_in[14];
    const float* W_g = (const float*)d_in[15];
    const float* b_g = (const float*)d_in[16];

    float* ws = (float*)d_ws;
    float* out = (float*)d_out;

    // workspace layout (float offsets):
    float* SC      = ws;                         // scores f32: 4,194,304 f (dead after softmax)
    short* attn_bf = (short*)(ws + 4194304);     // 4,194,304 shorts = 2,097,152 f
    short* Up0     = (short*)ws;                 // bf16 partials overlay dead SC:
    short* Up1     = (short*)(ws + 1048576);     //   each 2,097,152 shorts = 1,048,576 f
    short* Up2     = (short*)(ws + 2097152);
    short* Up3     = (short*)(ws + 3145728);     // ends 4,194,304 (SC region exactly)
    float* qbuf    = ws + 10485760;              // 8,192
    short* Amat_bf = (short*)(ws + 10493952);    // 65,536 f
    float* c0      = ws + 10559488;              // 256
    float* ctx     = ws + 10559744;              // 131,072
    float* pooled  = ws + 10690816;              // 131,072
    int*   ivals   = (int*)(ws + 11870464);
    int* totals = ivals;                         // 16
    int* rsrc = ivals + 16;                      // 1024
    int* flag = ivals + 16 + 1024;               // 16
    // post-ctx overlays (Up0..3 dead after ctx):
    short* lnv_bf = (short*)ws;                  // 1168*1024 shorts
    short* lng_bf = (short*)(ws + 622592);
    float* c1 = ws + 1245184;
    float* c2 = ws + 2441216;                    // ends 3,637,248 OK
    float* maskf = out + (size_t)Bn * Tn * Dn;

    const int M2 = Bn * Tn; // 1168

    setup1_kernel<<<2049, 256, 0, stream>>>(queries, in_w, in_b,
                                            (const unsigned char*)valid_raw, qbuf, flag);
    setup2_kernel<<<80, 256, 0, stream>>>(qbuf, in_w, in_b, valid_raw, flag,
                                          Amat_bf, c0, totals, rsrc, maskf);
    scores_mfma<<<(Bn * Sn) / 64, 256, 0, stream>>>(hidden, Amat_bf, c0, valid_raw, flag, SC);
    softmax_kernel<<<Bn * 128, 256, 0, stream>>>(SC, attn_bf);
    U_mfma<<<dim3(16, Bn, 4), 512, 0, stream>>>(attn_bf, hidden, Up0, Up1, Up2, Up3);
    ctx_mfma<<<Bn * Hn, 64, 0, stream>>>(Up0, Up1, Up2, Up3, in_w, in_b, ctx);
    pooled_mfma<<<dim3(2, 16), 256, 0, stream>>>(ctx, out_w, out_b, pooled, Bn * Pn);
    summary_ln_kernel<<<dim3(Bn, Tn), 256, 0, stream>>>(hidden, queries, pooled, rsrc,
                                                        ln_pma_g, ln_pma_b, ln_v_g, ln_v_b,
                                                        ln_g_g, ln_g_b, lnv_bf, lng_bf);
    wgemm_mfma<<<dim3((M2 + 63) / 64, 16, 2), 256, 0, stream>>>(lnv_bf, lng_bf, W_v, W_g,
                                                                b_v, b_g, c1, c2, M2);
    gated_kernel<<<(Bn * Tn * Dn) / 256, 256, 0, stream>>>(c1, c2, maskf, out);
}